// Round 7
// baseline (5531.889 us; speedup 1.0000x reference)
//
#include <hip/hip_runtime.h>
#include <math.h>

// GCN 5-layer on MI355X — bucket-grouped edges + LDS-accumulator aggregation.
// (Resubmit: container unresponsive before execution in prior rounds.)
// Buckets = 256 consecutive target nodes (NB = ceil(N/256) = 391).
// Pipeline:
//   k_count   : chunked LDS histogram of col>>8  (few global atomics)
//   k_bscan   : 391-entry scan -> off[], next[]
//   k_bscatter: pos = atomicAdd(next[bucket]); edat[pos] = {row | c_low<<20, w}
//   k_bdeg    : per-bucket LDS weighted degree -> dinv = rsqrt(deg+1)
//   k_agg6    : layer-1 aggregation on 6-wide features (A@(xW)==(A@x)@W),
//               computes nrm = dinv[r]*w*dinv[c] on the fly and writes it back to edat.y
//   k_gemm1   : 6->64 dense + sigmoid
//   3x (k_gemm64 ; k_bagg64): 64x64 GEMM, then bucket-LDS aggregation (ds_add_f32),
//               last agg fuses the W5 dot -> h5
//   k_bagg5   : scalar bucket aggregation + sigmoid + per-bucket partial sum
//   k_final   : mean
// Packing: edat.x = r | (c&255)<<20  (N < 2^20), edat.y = bits of w (later nrm).

__device__ __forceinline__ float sigf(float x) { return 1.0f / (1.0f + expf(-x)); }

#define RMASK 0xFFFFF

__global__ __launch_bounds__(256) void k_count(const int* __restrict__ col,
                                               int* __restrict__ gcnt, int E, int NB) {
  __shared__ int lc[512];
  int t = threadIdx.x;
  for (int i = t; i < NB; i += 256) lc[i] = 0;
  __syncthreads();
  int base = blockIdx.x * 8192;
  int hi = base + 8192; if (hi > E) hi = E;
  for (int e = base + t; e < hi; e += 256) atomicAdd(&lc[col[e] >> 8], 1);
  __syncthreads();
  for (int i = t; i < NB; i += 256)
    if (lc[i]) atomicAdd(&gcnt[i], lc[i]);
}

__global__ __launch_bounds__(512) void k_bscan(const int* __restrict__ gcnt,
                                               int* __restrict__ off,
                                               int* __restrict__ next, int NB) {
  __shared__ int s[512];
  int t = threadIdx.x;
  int v = (t < NB) ? gcnt[t] : 0;
  s[t] = v;
  __syncthreads();
  for (int d = 1; d < 512; d <<= 1) {
    int tmp = (t >= d) ? s[t - d] : 0;
    __syncthreads();
    s[t] += tmp;
    __syncthreads();
  }
  if (t < NB) { off[t] = s[t] - v; next[t] = s[t] - v; }
  if (t == 511) off[NB] = s[511];
}

__global__ __launch_bounds__(256) void k_bscatter(const int* __restrict__ row,
                                                  const int* __restrict__ col,
                                                  const float* __restrict__ w,
                                                  int* __restrict__ next,
                                                  int2* __restrict__ edat, int E) {
  int e = blockIdx.x * 256 + threadIdx.x;
  if (e < E) {
    int c = col[e];
    int pos = atomicAdd(&next[c >> 8], 1);
    edat[pos] = make_int2(row[e] | ((c & 255) << 20), __float_as_int(w[e]));
  }
}

__global__ __launch_bounds__(256) void k_bdeg(const int2* __restrict__ edat,
                                              const int* __restrict__ off,
                                              float* __restrict__ dinv, int N) {
  __shared__ float dl[256];
  int t = threadIdx.x, b = blockIdx.x;
  dl[t] = 0.0f;
  __syncthreads();
  int e0 = off[b], e1 = off[b + 1];
  for (int e = e0 + t; e < e1; e += 256) {
    int2 a = edat[e];
    atomicAdd(&dl[((unsigned)a.x) >> 20], __int_as_float(a.y));
  }
  __syncthreads();
  int node = b * 256 + t;
  if (node < N) dinv[node] = rsqrtf(dl[t] + 1.0f);
}

// Layer-1 aggregation on raw 6-wide features; computes and stores nrm into edat.y.
__global__ __launch_bounds__(256) void k_agg6(const float* __restrict__ vf,
                                              const float* __restrict__ dinv,
                                              const int* __restrict__ off,
                                              int2* __restrict__ edat,
                                              float* __restrict__ Sx, int N) {
  __shared__ float acc[256 * 6];
  __shared__ float dcl[256];
  int t = threadIdx.x, b = blockIdx.x;
  int node = b * 256 + t;
  float dv = (node < N) ? dinv[node] : 0.0f;
  dcl[t] = dv;
#pragma unroll
  for (int f = 0; f < 6; ++f)
    acc[t * 6 + f] = (node < N) ? dv * dv * vf[node * 6 + f] : 0.0f;
  __syncthreads();
  int e0 = off[b], e1 = off[b + 1];
  for (int e = e0 + t; e < e1; e += 256) {
    int2 a = edat[e];
    int r = a.x & RMASK;
    int cl = ((unsigned)a.x) >> 20;
    float nrm = dinv[r] * __int_as_float(a.y) * dcl[cl];
    edat[e].y = __float_as_int(nrm);
#pragma unroll
    for (int f = 0; f < 6; ++f) atomicAdd(&acc[cl * 6 + f], nrm * vf[r * 6 + f]);
  }
  __syncthreads();
  if (node < N) {
#pragma unroll
    for (int f = 0; f < 6; ++f) Sx[node * 6 + f] = acc[t * 6 + f];
  }
}

// X = sigmoid(Sx @ W1 + b1), Sx [N,6], W1 [6,64]
__global__ __launch_bounds__(256) void k_gemm1(const float* __restrict__ Sx,
                                               const float* __restrict__ W1,
                                               const float* __restrict__ b1,
                                               float* __restrict__ X, int N) {
  __shared__ float Wl[6 * 64];
  __shared__ float bl[64];
  __shared__ float XT[6 * 65];
  int t = threadIdx.x;
  int n0 = blockIdx.x * 64;
  for (int i = t; i < 384; i += 256) {
    Wl[i] = W1[i];
    int n = i / 6, k = i - n * 6;
    int node = n0 + n;
    XT[k * 65 + n] = (node < N) ? Sx[node * 6 + k] : 0.0f;
  }
  if (t < 64) bl[t] = b1[t];
  __syncthreads();
  int c0 = (t & 15) * 4;
  int nn = (t >> 4) * 4;
  float acc[4][4];
#pragma unroll
  for (int i = 0; i < 4; ++i)
#pragma unroll
    for (int j = 0; j < 4; ++j) acc[i][j] = bl[c0 + j];
#pragma unroll
  for (int k = 0; k < 6; ++k) {
    float4 wv = *(const float4*)&Wl[k * 64 + c0];
    float xv[4];
#pragma unroll
    for (int i = 0; i < 4; ++i) xv[i] = XT[k * 65 + nn + i];
#pragma unroll
    for (int i = 0; i < 4; ++i) {
      acc[i][0] += xv[i] * wv.x;
      acc[i][1] += xv[i] * wv.y;
      acc[i][2] += xv[i] * wv.z;
      acc[i][3] += xv[i] * wv.w;
    }
  }
#pragma unroll
  for (int i = 0; i < 4; ++i) {
    int node = n0 + nn + i;
    if (node < N) {
      float4 o;
      o.x = sigf(acc[i][0]); o.y = sigf(acc[i][1]);
      o.z = sigf(acc[i][2]); o.w = sigf(acc[i][3]);
      *(float4*)&X[node * 64 + c0] = o;
    }
  }
}

// H = X @ W  (X [N,64], W [64,64] row-major). 64x64 tile per block.
__global__ __launch_bounds__(256) void k_gemm64(const float* __restrict__ Xin,
                                                const float* __restrict__ W,
                                                float* __restrict__ Hout, int N) {
  __shared__ float XT[64 * 65];  // [k][n], padded
  __shared__ float Wl[64 * 64];  // [k][c]
  int t = threadIdx.x;
  int n0 = blockIdx.x * 64;
#pragma unroll
  for (int i = 0; i < 4; ++i) {
    int idx = (i * 256 + t) * 4;
    *(float4*)&Wl[idx] = *(const float4*)&W[idx];
  }
#pragma unroll
  for (int i = 0; i < 4; ++i) {
    int idx = (i * 256 + t) * 4;
    int n = idx >> 6, k = idx & 63;
    int node = n0 + n;
    float4 xv = make_float4(0.f, 0.f, 0.f, 0.f);
    if (node < N) xv = *(const float4*)&Xin[node * 64 + k];
    XT[k * 65 + n] = xv.x;
    XT[(k + 1) * 65 + n] = xv.y;
    XT[(k + 2) * 65 + n] = xv.z;
    XT[(k + 3) * 65 + n] = xv.w;
  }
  __syncthreads();
  int c0 = (t & 15) * 4;
  int nn = (t >> 4) * 4;
  float acc[4][4] = {{0.f}};
#pragma unroll
  for (int k = 0; k < 64; ++k) {
    float4 wv = *(const float4*)&Wl[k * 64 + c0];
    float xv[4];
#pragma unroll
    for (int i = 0; i < 4; ++i) xv[i] = XT[k * 65 + nn + i];
#pragma unroll
    for (int i = 0; i < 4; ++i) {
      acc[i][0] += xv[i] * wv.x;
      acc[i][1] += xv[i] * wv.y;
      acc[i][2] += xv[i] * wv.z;
      acc[i][3] += xv[i] * wv.w;
    }
  }
#pragma unroll
  for (int i = 0; i < 4; ++i) {
    int node = n0 + nn + i;
    if (node < N) {
      float4 o = make_float4(acc[i][0], acc[i][1], acc[i][2], acc[i][3]);
      *(float4*)&Hout[node * 64 + c0] = o;
    }
  }
}

// Bucket aggregation, 64-wide: block per bucket, acc[256][64] in LDS via ds_add_f32.
// LAST: fuse W5 dot -> h5.
template <bool LAST>
__global__ __launch_bounds__(1024) void k_bagg64(const float* __restrict__ Hin,
                                                 const float* __restrict__ dinv,
                                                 const int* __restrict__ off,
                                                 const int2* __restrict__ edat,
                                                 const float* __restrict__ bias,
                                                 const float* __restrict__ W5,
                                                 float* __restrict__ Xout,
                                                 float* __restrict__ h5, int N) {
  __shared__ float acc[256 * 64];  // 64 KB
  __shared__ float dsq[256];
  int t = threadIdx.x, lane = t & 63, wv = t >> 6;  // 16 waves
  int b = blockIdx.x;
  if (t < 256) {
    int node = b * 256 + t;
    float dv = (node < N) ? dinv[node] : 0.0f;
    dsq[t] = dv * dv;
  }
  __syncthreads();
  // init: self-loop contribution (coalesced 64 KB read)
  for (int j = wv; j < 256; j += 16) {
    int node = b * 256 + j;
    acc[j * 64 + lane] = (node < N) ? dsq[j] * Hin[node * 64 + lane] : 0.0f;
  }
  __syncthreads();
  int e0 = off[b], e1 = off[b + 1];
  int e = e0 + wv;
  for (; e + 48 < e1; e += 64) {  // 4-deep ILP per wave
    int2 a0 = edat[e];
    int2 a1 = edat[e + 16];
    int2 a2 = edat[e + 32];
    int2 a3 = edat[e + 48];
    float h0 = Hin[(a0.x & RMASK) * 64 + lane];
    float h1 = Hin[(a1.x & RMASK) * 64 + lane];
    float h2 = Hin[(a2.x & RMASK) * 64 + lane];
    float h3 = Hin[(a3.x & RMASK) * 64 + lane];
    atomicAdd(&acc[(((unsigned)a0.x) >> 20) * 64 + lane], __int_as_float(a0.y) * h0);
    atomicAdd(&acc[(((unsigned)a1.x) >> 20) * 64 + lane], __int_as_float(a1.y) * h1);
    atomicAdd(&acc[(((unsigned)a2.x) >> 20) * 64 + lane], __int_as_float(a2.y) * h2);
    atomicAdd(&acc[(((unsigned)a3.x) >> 20) * 64 + lane], __int_as_float(a3.y) * h3);
  }
  for (; e < e1; e += 16) {
    int2 a = edat[e];
    float hv = Hin[(a.x & RMASK) * 64 + lane];
    atomicAdd(&acc[(((unsigned)a.x) >> 20) * 64 + lane], __int_as_float(a.y) * hv);
  }
  __syncthreads();
  float bb = bias[lane];
  for (int j = wv; j < 256; j += 16) {
    int node = b * 256 + j;
    if (node >= N) continue;
    float v = sigf(acc[j * 64 + lane] + bb);
    if (LAST) {
      v *= W5[lane];
#pragma unroll
      for (int d = 32; d; d >>= 1) v += __shfl_xor(v, d);
      if (lane == 0) h5[node] = v;
    } else {
      Xout[node * 64 + lane] = v;
    }
  }
}

// Scalar bucket aggregation + sigmoid + per-bucket partial sum.
__global__ __launch_bounds__(256) void k_bagg5(const float* __restrict__ h5,
                                               const float* __restrict__ dinv,
                                               const int* __restrict__ off,
                                               const int2* __restrict__ edat,
                                               const float* __restrict__ b5,
                                               float* __restrict__ partials, int N) {
  __shared__ float a5[256];
  __shared__ float red[4];
  int t = threadIdx.x, b = blockIdx.x;
  int node = b * 256 + t;
  float dv = (node < N) ? dinv[node] : 0.0f;
  a5[t] = (node < N) ? dv * dv * h5[node] : 0.0f;
  __syncthreads();
  int e0 = off[b], e1 = off[b + 1];
  for (int e = e0 + t; e < e1; e += 256) {
    int2 a = edat[e];
    atomicAdd(&a5[((unsigned)a.x) >> 20], __int_as_float(a.y) * h5[a.x & RMASK]);
  }
  __syncthreads();
  float sig = (node < N) ? sigf(a5[t] + b5[0]) : 0.0f;
#pragma unroll
  for (int d = 32; d; d >>= 1) sig += __shfl_xor(sig, d);
  int lane = t & 63, wid = t >> 6;
  if (lane == 0) red[wid] = sig;
  __syncthreads();
  if (t == 0) partials[b] = red[0] + red[1] + red[2] + red[3];
}

__global__ __launch_bounds__(512) void k_final(const float* __restrict__ partials,
                                               float* __restrict__ out, int nb,
                                               float invN) {
  float v = 0.0f;
  for (int i = threadIdx.x; i < nb; i += 512) v += partials[i];
#pragma unroll
  for (int d = 32; d; d >>= 1) v += __shfl_xor(v, d);
  __shared__ float ws[8];
  int lane = threadIdx.x & 63, wid = threadIdx.x >> 6;
  if (lane == 0) ws[wid] = v;
  __syncthreads();
  if (threadIdx.x == 0) {
    float s = 0.0f;
    for (int i = 0; i < 8; ++i) s += ws[i];
    out[0] = s * invN;
  }
}

extern "C" void kernel_launch(void* const* d_in, const int* in_sizes, int n_in,
                              void* d_out, int out_size, void* d_ws, size_t ws_size,
                              hipStream_t stream) {
  const float* vf = (const float*)d_in[0];
  const int* edges = (const int*)d_in[1];
  const float* w = (const float*)d_in[2];
  const float* W1 = (const float*)d_in[3];
  const float* b1 = (const float*)d_in[4];
  const float* W2 = (const float*)d_in[5];
  const float* b2 = (const float*)d_in[6];
  const float* W3 = (const float*)d_in[7];
  const float* b3 = (const float*)d_in[8];
  const float* W4 = (const float*)d_in[9];
  const float* b4 = (const float*)d_in[10];
  const float* W5 = (const float*)d_in[11];
  const float* b5 = (const float*)d_in[12];
  float* out = (float*)d_out;

  const int N = in_sizes[0] / 6;
  const int E = in_sizes[2];
  const int* row = edges;
  const int* col = edges + E;
  const int NB = (N + 255) >> 8;  // 391 buckets of 256 target nodes

  size_t o = 0;
  auto carve = [&](size_t bytes) -> void* {
    void* p = (char*)d_ws + o;
    o += (bytes + 255) & ~(size_t)255;
    return p;
  };
  float* X = (float*)carve((size_t)N * 64 * 4);
  float* H = (float*)carve((size_t)N * 64 * 4);  // also holds Sx [N,6]
  int2* edat = (int2*)carve((size_t)E * 8);      // {r | c_low<<20, w|nrm}
  float* dinv = (float*)carve((size_t)N * 4);
  int* off = (int*)carve((size_t)(NB + 1) * 4);
  int* next = (int*)carve((size_t)NB * 4);
  int* cnt = (int*)carve((size_t)NB * 4);
  float* h5 = (float*)carve((size_t)N * 4);
  float* partials = (float*)carve((size_t)NB * 4);

  hipMemsetAsync(cnt, 0, (size_t)NB * 4, stream);

  const int eb = (E + 255) / 256;
  k_count<<<(E + 8191) / 8192, 256, 0, stream>>>(col, cnt, E, NB);
  k_bscan<<<1, 512, 0, stream>>>(cnt, off, next, NB);
  k_bscatter<<<eb, 256, 0, stream>>>(row, col, w, next, edat, E);
  k_bdeg<<<NB, 256, 0, stream>>>(edat, off, dinv, N);

  // layer 1: aggregate features (D=6) + compute/store nrm, then dense 6->64
  k_agg6<<<NB, 256, 0, stream>>>(vf, dinv, off, edat, H, N);
  k_gemm1<<<(N + 63) / 64, 256, 0, stream>>>(H, W1, b1, X, N);

  // layers 2-4
  k_gemm64<<<(N + 63) / 64, 256, 0, stream>>>(X, W2, H, N);
  k_bagg64<false><<<NB, 1024, 0, stream>>>(H, dinv, off, edat, b2, W5, X, h5, N);
  k_gemm64<<<(N + 63) / 64, 256, 0, stream>>>(X, W3, H, N);
  k_bagg64<false><<<NB, 1024, 0, stream>>>(H, dinv, off, edat, b3, W5, X, h5, N);
  k_gemm64<<<(N + 63) / 64, 256, 0, stream>>>(X, W4, H, N);
  k_bagg64<true><<<NB, 1024, 0, stream>>>(H, dinv, off, edat, b4, W5, X, h5, N);

  // layer 5: scalar aggregation + mean
  k_bagg5<<<NB, 256, 0, stream>>>(h5, dinv, off, edat, b5, partials, N);
  k_final<<<1, 512, 0, stream>>>(partials, out, NB, 1.0f / (float)N);
}

// Round 9
// 1834.328 us; speedup vs baseline: 3.0158x; 3.0158x over previous
//
#include <hip/hip_runtime.h>
#include <math.h>

// GCN 5-layer on MI355X — bucket scatter + per-bucket LDS counting sort
// -> per-node CSC, then the measured-fast wave-per-node gather aggregation.
// (Resubmit: container unresponsive before execution last round.)
// Pipeline:
//   k_count   : LDS histogram of col>>8 -> gcnt[NB]            (NB = ceil(N/256))
//   k_bscan   : scan NB buckets -> boff/bnext; offn[N] = E
//   k_bscatter: raw[pos] = {row | (col&255)<<20, w}  (391 append cursors)
//   k_bsort   : per bucket: LDS count+wsum per node, LDS scan -> offn[node],
//               dinv[node] = rsqrt(wsum+1); 2nd pass scatters edges sorted by
//               node into edat  => global per-node CSC, no per-node atomics.
//   k_agg6    : layer-1 agg on raw 6-wide features (A@(xW)==(A@x)@W); computes
//               nrm = dinv[r]*w*dinv[c] per edge and writes it back to edat.y
//   k_gemm1   : 6->64 dense + sigmoid
//   3x (k_gemm64 ; k_agg64): 64x64 f32 GEMM, wave-per-node CSC gather agg
//               (x4 unrolled); last agg fuses the W5 dot -> h5
//   k_agg5    : scalar CSC agg + sigmoid + block partial sums; k_final: mean
// raw[] overlays the H buffer (E*8 == N*64*4 bytes); H first used after k_agg6.

__device__ __forceinline__ float sigf(float x) { return 1.0f / (1.0f + expf(-x)); }

#define RMASK 0xFFFFF

__global__ __launch_bounds__(256) void k_count(const int* __restrict__ col,
                                               int* __restrict__ gcnt, int E, int NB) {
  __shared__ int lc[512];
  int t = threadIdx.x;
  for (int i = t; i < NB; i += 256) lc[i] = 0;
  __syncthreads();
  int base = blockIdx.x * 8192;
  int hi = base + 8192; if (hi > E) hi = E;
  for (int e = base + t; e < hi; e += 256) atomicAdd(&lc[col[e] >> 8], 1);
  __syncthreads();
  for (int i = t; i < NB; i += 256)
    if (lc[i]) atomicAdd(&gcnt[i], lc[i]);
}

__global__ __launch_bounds__(512) void k_bscan(const int* __restrict__ gcnt,
                                               int* __restrict__ boff,
                                               int* __restrict__ bnext,
                                               int* __restrict__ offn, int NB, int N) {
  __shared__ int s[512];
  int t = threadIdx.x;
  int v = (t < NB) ? gcnt[t] : 0;
  s[t] = v;
  __syncthreads();
  for (int d = 1; d < 512; d <<= 1) {
    int tmp = (t >= d) ? s[t - d] : 0;
    __syncthreads();
    s[t] += tmp;
    __syncthreads();
  }
  if (t < NB) { boff[t] = s[t] - v; bnext[t] = s[t] - v; }
  if (t == 511) { boff[NB] = s[511]; offn[N] = s[511]; }
}

__global__ __launch_bounds__(256) void k_bscatter(const int* __restrict__ row,
                                                  const int* __restrict__ col,
                                                  const float* __restrict__ w,
                                                  int* __restrict__ bnext,
                                                  int2* __restrict__ raw, int E) {
  int e = blockIdx.x * 256 + threadIdx.x;
  if (e < E) {
    int c = col[e];
    int pos = atomicAdd(&bnext[c >> 8], 1);
    raw[pos] = make_int2(row[e] | ((c & 255) << 20), __float_as_int(w[e]));
  }
}

// Per-bucket counting sort by local node id; emits offn[], dinv[], sorted edat.
__global__ __launch_bounds__(256) void k_bsort(const int2* __restrict__ raw,
                                               const int* __restrict__ boff,
                                               int2* __restrict__ edat,
                                               int* __restrict__ offn,
                                               float* __restrict__ dinv, int N) {
  __shared__ int cnt[256];
  __shared__ float wsum[256];
  __shared__ int s[256];
  __shared__ int pos[256];
  int t = threadIdx.x, b = blockIdx.x;
  int e0 = boff[b], e1 = boff[b + 1];
  cnt[t] = 0;
  wsum[t] = 0.0f;
  __syncthreads();
  for (int e = e0 + t; e < e1; e += 256) {
    int2 a = raw[e];
    int cl = ((unsigned)a.x) >> 20;
    atomicAdd(&cnt[cl], 1);
    atomicAdd(&wsum[cl], __int_as_float(a.y));
  }
  __syncthreads();
  int c = cnt[t];
  s[t] = c;
  __syncthreads();
  for (int d = 1; d < 256; d <<= 1) {
    int v = (t >= d) ? s[t - d] : 0;
    __syncthreads();
    s[t] += v;
    __syncthreads();
  }
  int excl = s[t] - c;
  int node = b * 256 + t;
  if (node < N) {
    dinv[node] = rsqrtf(wsum[t] + 1.0f);
    offn[node] = e0 + excl;
  }
  pos[t] = e0 + excl;
  __syncthreads();
  for (int e = e0 + t; e < e1; e += 256) {
    int2 a = raw[e];
    int p = atomicAdd(&pos[((unsigned)a.x) >> 20], 1);
    edat[p] = a;  // bucket range is L2-hot; write is contiguous per bucket
  }
}

// Layer-1 aggregation on 6-wide features; 8 lanes/node; writes nrm into edat.y.
__global__ __launch_bounds__(256) void k_agg6(const float* __restrict__ vf,
                                              const float* __restrict__ dinv,
                                              const int* __restrict__ offn,
                                              int2* __restrict__ edat,
                                              float* __restrict__ Sx, int N) {
  int t = threadIdx.x, g = t >> 3, f = t & 7;
  int node = blockIdx.x * 32 + g;
  if (node >= N) return;
  bool act = f < 6;
  float dc = dinv[node];
  float acc = act ? dc * dc * vf[node * 6 + f] : 0.0f;
  int e1 = offn[node + 1];
  for (int e = offn[node]; e < e1; ++e) {
    int2 a = edat[e];
    int r = a.x & RMASK;
    float nrm = dinv[r] * __int_as_float(a.y) * dc;
    if (f == 0) edat[e].y = __float_as_int(nrm);
    if (act) acc += nrm * vf[r * 6 + f];
  }
  if (act) Sx[node * 6 + f] = acc;
}

// X = sigmoid(Sx @ W1 + b1), Sx [N,6], W1 [6,64]
__global__ __launch_bounds__(256) void k_gemm1(const float* __restrict__ Sx,
                                               const float* __restrict__ W1,
                                               const float* __restrict__ b1,
                                               float* __restrict__ X, int N) {
  __shared__ float Wl[6 * 64];
  __shared__ float bl[64];
  __shared__ float XT[6 * 65];
  int t = threadIdx.x;
  int n0 = blockIdx.x * 64;
  for (int i = t; i < 384; i += 256) {
    Wl[i] = W1[i];
    int n = i / 6, k = i - n * 6;
    int node = n0 + n;
    XT[k * 65 + n] = (node < N) ? Sx[node * 6 + k] : 0.0f;
  }
  if (t < 64) bl[t] = b1[t];
  __syncthreads();
  int c0 = (t & 15) * 4;
  int nn = (t >> 4) * 4;
  float acc[4][4];
#pragma unroll
  for (int i = 0; i < 4; ++i)
#pragma unroll
    for (int j = 0; j < 4; ++j) acc[i][j] = bl[c0 + j];
#pragma unroll
  for (int k = 0; k < 6; ++k) {
    float4 wv = *(const float4*)&Wl[k * 64 + c0];
    float xv[4];
#pragma unroll
    for (int i = 0; i < 4; ++i) xv[i] = XT[k * 65 + nn + i];
#pragma unroll
    for (int i = 0; i < 4; ++i) {
      acc[i][0] += xv[i] * wv.x;
      acc[i][1] += xv[i] * wv.y;
      acc[i][2] += xv[i] * wv.z;
      acc[i][3] += xv[i] * wv.w;
    }
  }
#pragma unroll
  for (int i = 0; i < 4; ++i) {
    int node = n0 + nn + i;
    if (node < N) {
      float4 o;
      o.x = sigf(acc[i][0]); o.y = sigf(acc[i][1]);
      o.z = sigf(acc[i][2]); o.w = sigf(acc[i][3]);
      *(float4*)&X[node * 64 + c0] = o;
    }
  }
}

// H = X @ W  (X [N,64], W [64,64] row-major). 64x64 tile per block.
__global__ __launch_bounds__(256) void k_gemm64(const float* __restrict__ Xin,
                                                const float* __restrict__ W,
                                                float* __restrict__ Hout, int N) {
  __shared__ float XT[64 * 65];
  __shared__ float Wl[64 * 64];
  int t = threadIdx.x;
  int n0 = blockIdx.x * 64;
#pragma unroll
  for (int i = 0; i < 4; ++i) {
    int idx = (i * 256 + t) * 4;
    *(float4*)&Wl[idx] = *(const float4*)&W[idx];
  }
#pragma unroll
  for (int i = 0; i < 4; ++i) {
    int idx = (i * 256 + t) * 4;
    int n = idx >> 6, k = idx & 63;
    int node = n0 + n;
    float4 xv = make_float4(0.f, 0.f, 0.f, 0.f);
    if (node < N) xv = *(const float4*)&Xin[node * 64 + k];
    XT[k * 65 + n] = xv.x;
    XT[(k + 1) * 65 + n] = xv.y;
    XT[(k + 2) * 65 + n] = xv.z;
    XT[(k + 3) * 65 + n] = xv.w;
  }
  __syncthreads();
  int c0 = (t & 15) * 4;
  int nn = (t >> 4) * 4;
  float acc[4][4] = {{0.f}};
#pragma unroll
  for (int k = 0; k < 64; ++k) {
    float4 wv = *(const float4*)&Wl[k * 64 + c0];
    float xv[4];
#pragma unroll
    for (int i = 0; i < 4; ++i) xv[i] = XT[k * 65 + nn + i];
#pragma unroll
    for (int i = 0; i < 4; ++i) {
      acc[i][0] += xv[i] * wv.x;
      acc[i][1] += xv[i] * wv.y;
      acc[i][2] += xv[i] * wv.z;
      acc[i][3] += xv[i] * wv.w;
    }
  }
#pragma unroll
  for (int i = 0; i < 4; ++i) {
    int node = n0 + nn + i;
    if (node < N) {
      float4 o = make_float4(acc[i][0], acc[i][1], acc[i][2], acc[i][3]);
      *(float4*)&Hout[node * 64 + c0] = o;
    }
  }
}

// Wave-per-node CSC gather aggregation, x4 unrolled. LAST: fuse W5 dot -> h5.
template <bool LAST>
__global__ __launch_bounds__(256) void k_agg64(const float* __restrict__ Hin,
                                               const float* __restrict__ dinv,
                                               const int* __restrict__ offn,
                                               const int2* __restrict__ edat,
                                               const float* __restrict__ b,
                                               const float* __restrict__ W5,
                                               float* __restrict__ Xout,
                                               float* __restrict__ h5, int N) {
  int lane = threadIdx.x & 63;
  int wid = threadIdx.x >> 6;
  int node = blockIdx.x * 4 + wid;
  if (node >= N) return;
  float di = dinv[node];
  float acc = di * di * Hin[node * 64 + lane];  // self-loop
  int e = offn[node], e1 = offn[node + 1];
  for (; e + 3 < e1; e += 4) {
    int2 a0 = edat[e];
    int2 a1 = edat[e + 1];
    int2 a2 = edat[e + 2];
    int2 a3 = edat[e + 3];
    float h0 = Hin[(a0.x & RMASK) * 64 + lane];
    float h1 = Hin[(a1.x & RMASK) * 64 + lane];
    float h2 = Hin[(a2.x & RMASK) * 64 + lane];
    float h3 = Hin[(a3.x & RMASK) * 64 + lane];
    acc += __int_as_float(a0.y) * h0 + __int_as_float(a1.y) * h1 +
           __int_as_float(a2.y) * h2 + __int_as_float(a3.y) * h3;
  }
  for (; e < e1; ++e) {
    int2 a = edat[e];
    acc += __int_as_float(a.y) * Hin[(a.x & RMASK) * 64 + lane];
  }
  float xv = sigf(acc + b[lane]);
  if (LAST) {
    float v = xv * W5[lane];
#pragma unroll
    for (int d = 32; d; d >>= 1) v += __shfl_xor(v, d);
    if (lane == 0) h5[node] = v;
  } else {
    Xout[node * 64 + lane] = xv;
  }
}

// scalar CSC aggregation + sigmoid + per-block partial sum
__global__ __launch_bounds__(256) void k_agg5(const float* __restrict__ h5,
                                              const float* __restrict__ dinv,
                                              const int* __restrict__ offn,
                                              const int2* __restrict__ edat,
                                              const float* __restrict__ b5,
                                              float* __restrict__ partials, int N) {
  int n = blockIdx.x * 256 + threadIdx.x;
  float sig = 0.0f;
  if (n < N) {
    float di = dinv[n];
    float acc = di * di * h5[n];
    int e1 = offn[n + 1];
    for (int e = offn[n]; e < e1; ++e) {
      int2 a = edat[e];
      acc += __int_as_float(a.y) * h5[a.x & RMASK];
    }
    sig = sigf(acc + b5[0]);
  }
#pragma unroll
  for (int d = 32; d; d >>= 1) sig += __shfl_xor(sig, d);
  __shared__ float ws[4];
  int lane = threadIdx.x & 63, wid = threadIdx.x >> 6;
  if (lane == 0) ws[wid] = sig;
  __syncthreads();
  if (threadIdx.x == 0) partials[blockIdx.x] = ws[0] + ws[1] + ws[2] + ws[3];
}

__global__ __launch_bounds__(512) void k_final(const float* __restrict__ partials,
                                               float* __restrict__ out, int nb,
                                               float invN) {
  float v = 0.0f;
  for (int i = threadIdx.x; i < nb; i += 512) v += partials[i];
#pragma unroll
  for (int d = 32; d; d >>= 1) v += __shfl_xor(v, d);
  __shared__ float ws[8];
  int lane = threadIdx.x & 63, wid = threadIdx.x >> 6;
  if (lane == 0) ws[wid] = v;
  __syncthreads();
  if (threadIdx.x == 0) {
    float s = 0.0f;
    for (int i = 0; i < 8; ++i) s += ws[i];
    out[0] = s * invN;
  }
}

extern "C" void kernel_launch(void* const* d_in, const int* in_sizes, int n_in,
                              void* d_out, int out_size, void* d_ws, size_t ws_size,
                              hipStream_t stream) {
  const float* vf = (const float*)d_in[0];
  const int* edges = (const int*)d_in[1];
  const float* w = (const float*)d_in[2];
  const float* W1 = (const float*)d_in[3];
  const float* b1 = (const float*)d_in[4];
  const float* W2 = (const float*)d_in[5];
  const float* b2 = (const float*)d_in[6];
  const float* W3 = (const float*)d_in[7];
  const float* b3 = (const float*)d_in[8];
  const float* W4 = (const float*)d_in[9];
  const float* b4 = (const float*)d_in[10];
  const float* W5 = (const float*)d_in[11];
  const float* b5 = (const float*)d_in[12];
  float* out = (float*)d_out;

  const int N = in_sizes[0] / 6;
  const int E = in_sizes[2];
  const int* row = edges;
  const int* col = edges + E;
  const int NB = (N + 255) >> 8;

  size_t o = 0;
  auto carve = [&](size_t bytes) -> void* {
    void* p = (char*)d_ws + o;
    o += (bytes + 255) & ~(size_t)255;
    return p;
  };
  float* X = (float*)carve((size_t)N * 64 * 4);
  size_t hbytes = (size_t)N * 64 * 4;
  size_t rbytes = (size_t)E * 8;
  float* H = (float*)carve(hbytes > rbytes ? hbytes : rbytes);  // raw overlays H
  int2* raw = (int2*)H;
  int2* edat = (int2*)carve((size_t)E * 8);
  float* Sx = (float*)carve((size_t)N * 6 * 4);
  float* dinv = (float*)carve((size_t)N * 4);
  int* boff = (int*)carve((size_t)(NB + 1) * 4);
  int* bnext = (int*)carve((size_t)NB * 4);
  int* gcnt = (int*)carve((size_t)NB * 4);
  int* offn = (int*)carve((size_t)(N + 1) * 4);
  float* h5 = (float*)carve((size_t)N * 4);
  const int nb5 = (N + 255) / 256;
  float* partials = (float*)carve((size_t)nb5 * 4);

  hipMemsetAsync(gcnt, 0, (size_t)NB * 4, stream);

  const int eb = (E + 255) / 256;
  k_count<<<(E + 8191) / 8192, 256, 0, stream>>>(col, gcnt, E, NB);
  k_bscan<<<1, 512, 0, stream>>>(gcnt, boff, bnext, offn, NB, N);
  k_bscatter<<<eb, 256, 0, stream>>>(row, col, w, bnext, raw, E);
  k_bsort<<<NB, 256, 0, stream>>>(raw, boff, edat, offn, dinv, N);

  // layer 1: aggregate features (D=6) + compute/store nrm, then dense 6->64
  k_agg6<<<(N + 31) / 32, 256, 0, stream>>>(vf, dinv, offn, edat, Sx, N);
  k_gemm1<<<(N + 63) / 64, 256, 0, stream>>>(Sx, W1, b1, X, N);

  // layers 2-4 (H overwrites raw, which is fully consumed by k_bsort)
  const int nb4 = (N + 3) / 4;
  k_gemm64<<<(N + 63) / 64, 256, 0, stream>>>(X, W2, H, N);
  k_agg64<false><<<nb4, 256, 0, stream>>>(H, dinv, offn, edat, b2, W5, X, h5, N);
  k_gemm64<<<(N + 63) / 64, 256, 0, stream>>>(X, W3, H, N);
  k_agg64<false><<<nb4, 256, 0, stream>>>(H, dinv, offn, edat, b3, W5, X, h5, N);
  k_gemm64<<<(N + 63) / 64, 256, 0, stream>>>(X, W4, H, N);
  k_agg64<true><<<nb4, 256, 0, stream>>>(H, dinv, offn, edat, b4, W5, X, h5, N);

  // layer 5: scalar aggregation + mean
  k_agg5<<<nb5, 256, 0, stream>>>(h5, dinv, offn, edat, b5, partials, N);
  k_final<<<1, 512, 0, stream>>>(partials, out, nb5, 1.0f / (float)N);
}

// Round 10
// 886.213 us; speedup vs baseline: 6.2422x; 2.0699x over previous
//
#include <hip/hip_runtime.h>
#include <math.h>

// GCN 5-layer on MI355X — round 10: sub-bucket scatter (contention fix) +
// per-bucket LDS counting sort -> per-node CSC -> wave-per-node gather agg.
// R9 lesson: 391 append cursors = 8200 serialized atomics/line = 1108us.
// Fix: 16 sub-cursors per bucket keyed by edge chunk (e>>13)&15 -> 6256 cursors,
// ~512 atomics each; bucket ranges stay contiguous so k_bsort is unchanged.
// Pipeline:
//   k_count   : per-8192-chunk LDS histogram of col>>8 -> gcnt[b*16+sub]
//   k_bscan   : scan NB*16 cursors -> boff/bnext; offn[N] = E
//   k_bscatter: pos = atomicAdd(next[(c>>8)*16+sub]); raw[pos] = {r|(c&255)<<20, w}
//   k_bsort   : per bucket LDS count+wsum+scan -> offn/dinv, scatter sorted edat
//   k_agg6    : layer-1 agg on 6-wide features (A@(xW)==(A@x)@W); writes nrm->edat.y
//   k_gemm1   : 6->64 dense + sigmoid
//   3x (k_gemm64 ; k_agg64): 64x64 f32 GEMM + CSC gather agg (x4 unrolled);
//               last agg fuses the W5 dot -> h5
//   k_agg5/k_final: scalar CSC agg + sigmoid + mean
// raw[] overlays H (E*8 == N*64*4); H first written after raw is consumed.

__device__ __forceinline__ float sigf(float x) { return 1.0f / (1.0f + expf(-x)); }

#define RMASK 0xFFFFF
#define SUBS 16           // sub-cursors per bucket
#define CHUNK_SHIFT 13    // 8192 edges per count-chunk

__global__ __launch_bounds__(256) void k_count(const int* __restrict__ col,
                                               int* __restrict__ gcnt, int E, int NB) {
  __shared__ int lc[512];
  int t = threadIdx.x;
  for (int i = t; i < NB; i += 256) lc[i] = 0;
  __syncthreads();
  int base = blockIdx.x << CHUNK_SHIFT;
  int sub = blockIdx.x & (SUBS - 1);
  int hi = base + (1 << CHUNK_SHIFT); if (hi > E) hi = E;
  for (int e = base + t; e < hi; e += 256) atomicAdd(&lc[col[e] >> 8], 1);
  __syncthreads();
  for (int i = t; i < NB; i += 256)
    if (lc[i]) atomicAdd(&gcnt[i * SUBS + sub], lc[i]);
}

// scan M = NB*SUBS counters (<= 8192) with one 1024-thread block
__global__ __launch_bounds__(1024) void k_bscan(const int* __restrict__ gcnt,
                                                int* __restrict__ boff,
                                                int* __restrict__ bnext,
                                                int* __restrict__ offn, int M, int N) {
  __shared__ int s[1024];
  int t = threadIdx.x;
  int chunk = (M + 1023) / 1024;
  int lo = t * chunk; if (lo > M) lo = M;
  int hi = lo + chunk; if (hi > M) hi = M;
  int sum = 0;
  for (int i = lo; i < hi; ++i) sum += gcnt[i];
  s[t] = sum;
  __syncthreads();
  for (int d = 1; d < 1024; d <<= 1) {
    int v = (t >= d) ? s[t - d] : 0;
    __syncthreads();
    s[t] += v;
    __syncthreads();
  }
  int run = s[t] - sum;
  for (int i = lo; i < hi; ++i) {
    int c = gcnt[i];
    boff[i] = run;
    bnext[i] = run;
    run += c;
  }
  if (t == 1023) { boff[M] = s[1023]; offn[N] = s[1023]; }
}

__global__ __launch_bounds__(256) void k_bscatter(const int* __restrict__ row,
                                                  const int* __restrict__ col,
                                                  const float* __restrict__ w,
                                                  int* __restrict__ bnext,
                                                  int2* __restrict__ raw, int E) {
  int e = blockIdx.x * 256 + threadIdx.x;
  if (e < E) {
    int c = col[e];
    int sub = (e >> CHUNK_SHIFT) & (SUBS - 1);
    int pos = atomicAdd(&bnext[(c >> 8) * SUBS + sub], 1);
    raw[pos] = make_int2(row[e] | ((c & 255) << 20), __float_as_int(w[e]));
  }
}

// Per-bucket counting sort by local node id; emits offn[], dinv[], sorted edat.
__global__ __launch_bounds__(256) void k_bsort(const int2* __restrict__ raw,
                                               const int* __restrict__ boff,
                                               int2* __restrict__ edat,
                                               int* __restrict__ offn,
                                               float* __restrict__ dinv, int N) {
  __shared__ int cnt[256];
  __shared__ float wsum[256];
  __shared__ int s[256];
  __shared__ int pos[256];
  int t = threadIdx.x, b = blockIdx.x;
  int e0 = boff[b * SUBS], e1 = boff[(b + 1) * SUBS];
  cnt[t] = 0;
  wsum[t] = 0.0f;
  __syncthreads();
  for (int e = e0 + t; e < e1; e += 256) {
    int2 a = raw[e];
    int cl = ((unsigned)a.x) >> 20;
    atomicAdd(&cnt[cl], 1);
    atomicAdd(&wsum[cl], __int_as_float(a.y));
  }
  __syncthreads();
  int c = cnt[t];
  s[t] = c;
  __syncthreads();
  for (int d = 1; d < 256; d <<= 1) {
    int v = (t >= d) ? s[t - d] : 0;
    __syncthreads();
    s[t] += v;
    __syncthreads();
  }
  int excl = s[t] - c;
  int node = b * 256 + t;
  if (node < N) {
    dinv[node] = rsqrtf(wsum[t] + 1.0f);
    offn[node] = e0 + excl;
  }
  pos[t] = e0 + excl;
  __syncthreads();
  for (int e = e0 + t; e < e1; e += 256) {
    int2 a = raw[e];
    int p = atomicAdd(&pos[((unsigned)a.x) >> 20], 1);
    edat[p] = a;  // bucket range is L2-hot; write contiguous per node
  }
}

// Layer-1 aggregation on 6-wide features; 8 lanes/node; writes nrm into edat.y.
__global__ __launch_bounds__(256) void k_agg6(const float* __restrict__ vf,
                                              const float* __restrict__ dinv,
                                              const int* __restrict__ offn,
                                              int2* __restrict__ edat,
                                              float* __restrict__ Sx, int N) {
  int t = threadIdx.x, g = t >> 3, f = t & 7;
  int node = blockIdx.x * 32 + g;
  if (node >= N) return;
  bool act = f < 6;
  float dc = dinv[node];
  float acc = act ? dc * dc * vf[node * 6 + f] : 0.0f;
  int e1 = offn[node + 1];
  for (int e = offn[node]; e < e1; ++e) {
    int2 a = edat[e];
    int r = a.x & RMASK;
    float nrm = dinv[r] * __int_as_float(a.y) * dc;
    if (f == 0) edat[e].y = __float_as_int(nrm);
    if (act) acc += nrm * vf[r * 6 + f];
  }
  if (act) Sx[node * 6 + f] = acc;
}

// X = sigmoid(Sx @ W1 + b1), Sx [N,6], W1 [6,64]
__global__ __launch_bounds__(256) void k_gemm1(const float* __restrict__ Sx,
                                               const float* __restrict__ W1,
                                               const float* __restrict__ b1,
                                               float* __restrict__ X, int N) {
  __shared__ float Wl[6 * 64];
  __shared__ float bl[64];
  __shared__ float XT[6 * 65];
  int t = threadIdx.x;
  int n0 = blockIdx.x * 64;
  for (int i = t; i < 384; i += 256) {
    Wl[i] = W1[i];
    int n = i / 6, k = i - n * 6;
    int node = n0 + n;
    XT[k * 65 + n] = (node < N) ? Sx[node * 6 + k] : 0.0f;
  }
  if (t < 64) bl[t] = b1[t];
  __syncthreads();
  int c0 = (t & 15) * 4;
  int nn = (t >> 4) * 4;
  float acc[4][4];
#pragma unroll
  for (int i = 0; i < 4; ++i)
#pragma unroll
    for (int j = 0; j < 4; ++j) acc[i][j] = bl[c0 + j];
#pragma unroll
  for (int k = 0; k < 6; ++k) {
    float4 wv = *(const float4*)&Wl[k * 64 + c0];
    float xv[4];
#pragma unroll
    for (int i = 0; i < 4; ++i) xv[i] = XT[k * 65 + nn + i];
#pragma unroll
    for (int i = 0; i < 4; ++i) {
      acc[i][0] += xv[i] * wv.x;
      acc[i][1] += xv[i] * wv.y;
      acc[i][2] += xv[i] * wv.z;
      acc[i][3] += xv[i] * wv.w;
    }
  }
#pragma unroll
  for (int i = 0; i < 4; ++i) {
    int node = n0 + nn + i;
    if (node < N) {
      float4 o;
      o.x = sigf(acc[i][0]); o.y = sigf(acc[i][1]);
      o.z = sigf(acc[i][2]); o.w = sigf(acc[i][3]);
      *(float4*)&X[node * 64 + c0] = o;
    }
  }
}

// H = X @ W  (X [N,64], W [64,64] row-major). 64x64 tile per block.
__global__ __launch_bounds__(256) void k_gemm64(const float* __restrict__ Xin,
                                                const float* __restrict__ W,
                                                float* __restrict__ Hout, int N) {
  __shared__ float XT[64 * 65];
  __shared__ float Wl[64 * 64];
  int t = threadIdx.x;
  int n0 = blockIdx.x * 64;
#pragma unroll
  for (int i = 0; i < 4; ++i) {
    int idx = (i * 256 + t) * 4;
    *(float4*)&Wl[idx] = *(const float4*)&W[idx];
  }
#pragma unroll
  for (int i = 0; i < 4; ++i) {
    int idx = (i * 256 + t) * 4;
    int n = idx >> 6, k = idx & 63;
    int node = n0 + n;
    float4 xv = make_float4(0.f, 0.f, 0.f, 0.f);
    if (node < N) xv = *(const float4*)&Xin[node * 64 + k];
    XT[k * 65 + n] = xv.x;
    XT[(k + 1) * 65 + n] = xv.y;
    XT[(k + 2) * 65 + n] = xv.z;
    XT[(k + 3) * 65 + n] = xv.w;
  }
  __syncthreads();
  int c0 = (t & 15) * 4;
  int nn = (t >> 4) * 4;
  float acc[4][4] = {{0.f}};
#pragma unroll
  for (int k = 0; k < 64; ++k) {
    float4 wv = *(const float4*)&Wl[k * 64 + c0];
    float xv[4];
#pragma unroll
    for (int i = 0; i < 4; ++i) xv[i] = XT[k * 65 + nn + i];
#pragma unroll
    for (int i = 0; i < 4; ++i) {
      acc[i][0] += xv[i] * wv.x;
      acc[i][1] += xv[i] * wv.y;
      acc[i][2] += xv[i] * wv.z;
      acc[i][3] += xv[i] * wv.w;
    }
  }
#pragma unroll
  for (int i = 0; i < 4; ++i) {
    int node = n0 + nn + i;
    if (node < N) {
      float4 o = make_float4(acc[i][0], acc[i][1], acc[i][2], acc[i][3]);
      *(float4*)&Hout[node * 64 + c0] = o;
    }
  }
}

// Wave-per-node CSC gather aggregation, x4 unrolled. LAST: fuse W5 dot -> h5.
template <bool LAST>
__global__ __launch_bounds__(256) void k_agg64(const float* __restrict__ Hin,
                                               const float* __restrict__ dinv,
                                               const int* __restrict__ offn,
                                               const int2* __restrict__ edat,
                                               const float* __restrict__ b,
                                               const float* __restrict__ W5,
                                               float* __restrict__ Xout,
                                               float* __restrict__ h5, int N) {
  int lane = threadIdx.x & 63;
  int wid = threadIdx.x >> 6;
  int node = blockIdx.x * 4 + wid;
  if (node >= N) return;
  float di = dinv[node];
  float acc = di * di * Hin[node * 64 + lane];  // self-loop
  int e = offn[node], e1 = offn[node + 1];
  for (; e + 3 < e1; e += 4) {
    int2 a0 = edat[e];
    int2 a1 = edat[e + 1];
    int2 a2 = edat[e + 2];
    int2 a3 = edat[e + 3];
    float h0 = Hin[(a0.x & RMASK) * 64 + lane];
    float h1 = Hin[(a1.x & RMASK) * 64 + lane];
    float h2 = Hin[(a2.x & RMASK) * 64 + lane];
    float h3 = Hin[(a3.x & RMASK) * 64 + lane];
    acc += __int_as_float(a0.y) * h0 + __int_as_float(a1.y) * h1 +
           __int_as_float(a2.y) * h2 + __int_as_float(a3.y) * h3;
  }
  for (; e < e1; ++e) {
    int2 a = edat[e];
    acc += __int_as_float(a.y) * Hin[(a.x & RMASK) * 64 + lane];
  }
  float xv = sigf(acc + b[lane]);
  if (LAST) {
    float v = xv * W5[lane];
#pragma unroll
    for (int d = 32; d; d >>= 1) v += __shfl_xor(v, d);
    if (lane == 0) h5[node] = v;
  } else {
    Xout[node * 64 + lane] = xv;
  }
}

// scalar CSC aggregation + sigmoid + per-block partial sum
__global__ __launch_bounds__(256) void k_agg5(const float* __restrict__ h5,
                                              const float* __restrict__ dinv,
                                              const int* __restrict__ offn,
                                              const int2* __restrict__ edat,
                                              const float* __restrict__ b5,
                                              float* __restrict__ partials, int N) {
  int n = blockIdx.x * 256 + threadIdx.x;
  float sig = 0.0f;
  if (n < N) {
    float di = dinv[n];
    float acc = di * di * h5[n];
    int e1 = offn[n + 1];
    for (int e = offn[n]; e < e1; ++e) {
      int2 a = edat[e];
      acc += __int_as_float(a.y) * h5[a.x & RMASK];
    }
    sig = sigf(acc + b5[0]);
  }
#pragma unroll
  for (int d = 32; d; d >>= 1) sig += __shfl_xor(sig, d);
  __shared__ float ws[4];
  int lane = threadIdx.x & 63, wid = threadIdx.x >> 6;
  if (lane == 0) ws[wid] = sig;
  __syncthreads();
  if (threadIdx.x == 0) partials[blockIdx.x] = ws[0] + ws[1] + ws[2] + ws[3];
}

__global__ __launch_bounds__(512) void k_final(const float* __restrict__ partials,
                                               float* __restrict__ out, int nb,
                                               float invN) {
  float v = 0.0f;
  for (int i = threadIdx.x; i < nb; i += 512) v += partials[i];
#pragma unroll
  for (int d = 32; d; d >>= 1) v += __shfl_xor(v, d);
  __shared__ float ws[8];
  int lane = threadIdx.x & 63, wid = threadIdx.x >> 6;
  if (lane == 0) ws[wid] = v;
  __syncthreads();
  if (threadIdx.x == 0) {
    float s = 0.0f;
    for (int i = 0; i < 8; ++i) s += ws[i];
    out[0] = s * invN;
  }
}

extern "C" void kernel_launch(void* const* d_in, const int* in_sizes, int n_in,
                              void* d_out, int out_size, void* d_ws, size_t ws_size,
                              hipStream_t stream) {
  const float* vf = (const float*)d_in[0];
  const int* edges = (const int*)d_in[1];
  const float* w = (const float*)d_in[2];
  const float* W1 = (const float*)d_in[3];
  const float* b1 = (const float*)d_in[4];
  const float* W2 = (const float*)d_in[5];
  const float* b2 = (const float*)d_in[6];
  const float* W3 = (const float*)d_in[7];
  const float* b3 = (const float*)d_in[8];
  const float* W4 = (const float*)d_in[9];
  const float* b4 = (const float*)d_in[10];
  const float* W5 = (const float*)d_in[11];
  const float* b5 = (const float*)d_in[12];
  float* out = (float*)d_out;

  const int N = in_sizes[0] / 6;
  const int E = in_sizes[2];
  const int* row = edges;
  const int* col = edges + E;
  const int NB = (N + 255) >> 8;
  const int M = NB * SUBS;  // sub-bucket cursor count

  size_t o = 0;
  auto carve = [&](size_t bytes) -> void* {
    void* p = (char*)d_ws + o;
    o += (bytes + 255) & ~(size_t)255;
    return p;
  };
  float* X = (float*)carve((size_t)N * 64 * 4);
  size_t hbytes = (size_t)N * 64 * 4;
  size_t rbytes = (size_t)E * 8;
  float* H = (float*)carve(hbytes > rbytes ? hbytes : rbytes);  // raw overlays H
  int2* raw = (int2*)H;
  int2* edat = (int2*)carve((size_t)E * 8);
  float* Sx = (float*)carve((size_t)N * 6 * 4);
  float* dinv = (float*)carve((size_t)N * 4);
  int* boff = (int*)carve((size_t)(M + 1) * 4);
  int* bnext = (int*)carve((size_t)M * 4);
  int* gcnt = (int*)carve((size_t)M * 4);
  int* offn = (int*)carve((size_t)(N + 1) * 4);
  float* h5 = (float*)carve((size_t)N * 4);
  const int nb5 = (N + 255) / 256;
  float* partials = (float*)carve((size_t)nb5 * 4);

  hipMemsetAsync(gcnt, 0, (size_t)M * 4, stream);

  const int eb = (E + 255) / 256;
  k_count<<<(E + 8191) / 8192, 256, 0, stream>>>(col, gcnt, E, NB);
  k_bscan<<<1, 1024, 0, stream>>>(gcnt, boff, bnext, offn, M, N);
  k_bscatter<<<eb, 256, 0, stream>>>(row, col, w, bnext, raw, E);
  k_bsort<<<NB, 256, 0, stream>>>(raw, boff, edat, offn, dinv, N);

  // layer 1: aggregate features (D=6) + compute/store nrm, then dense 6->64
  k_agg6<<<(N + 31) / 32, 256, 0, stream>>>(vf, dinv, offn, edat, Sx, N);
  k_gemm1<<<(N + 63) / 64, 256, 0, stream>>>(Sx, W1, b1, X, N);

  // layers 2-4 (H overwrites raw, which is fully consumed by k_bsort)
  const int nb4 = (N + 3) / 4;
  k_gemm64<<<(N + 63) / 64, 256, 0, stream>>>(X, W2, H, N);
  k_agg64<false><<<nb4, 256, 0, stream>>>(H, dinv, offn, edat, b2, W5, X, h5, N);
  k_gemm64<<<(N + 63) / 64, 256, 0, stream>>>(X, W3, H, N);
  k_agg64<false><<<nb4, 256, 0, stream>>>(H, dinv, offn, edat, b3, W5, X, h5, N);
  k_gemm64<<<(N + 63) / 64, 256, 0, stream>>>(X, W4, H, N);
  k_agg64<true><<<nb4, 256, 0, stream>>>(H, dinv, offn, edat, b4, W5, X, h5, N);

  // layer 5: scalar aggregation + mean
  k_agg5<<<nb5, 256, 0, stream>>>(h5, dinv, offn, edat, b5, partials, N);
  k_final<<<1, 512, 0, stream>>>(partials, out, nb5, 1.0f / (float)N);
}

// Round 11
// 601.543 us; speedup vs baseline: 9.1962x; 1.4732x over previous
//
#include <hip/hip_runtime.h>
#include <hip/hip_fp16.h>
#include <math.h>

// GCN 5-layer on MI355X — round 11:
//  (a) tile-sorted scatter: per-8192-edge block LDS-sorts by bucket, reserves
//      contiguous runs via ONE atomic per (block,bucket) on line-padded cursors,
//      writes ~21-edge contiguous runs  -> kills the 7x write amplification.
//  (b) fp16 H: gemm64 stores half, agg64 gathers half2 (128B/row, half traffic).
// Everything else as R10 (measured-good): bucket CSC via k_bsort, CSC gather agg.

__device__ __forceinline__ float sigf(float x) { return 1.0f / (1.0f + expf(-x)); }

#define RMASK 0xFFFFF
#define SUBS 8            // cursor streams per bucket (blockIdx & 7)
#define TILE_SHIFT 13     // 8192 edges per tile
#define NBMAX 512

__global__ __launch_bounds__(256) void k_count(const int* __restrict__ col,
                                               int* __restrict__ gcnt, int E, int NB) {
  __shared__ int lc[NBMAX];
  int t = threadIdx.x;
  for (int i = t; i < NB; i += 256) lc[i] = 0;
  __syncthreads();
  int base = blockIdx.x << TILE_SHIFT;
  int sub = blockIdx.x & (SUBS - 1);
  int hi = base + (1 << TILE_SHIFT); if (hi > E) hi = E;
  for (int e = base + t; e < hi; e += 256) atomicAdd(&lc[col[e] >> 8], 1);
  __syncthreads();
  for (int i = t; i < NB; i += 256)
    if (lc[i]) atomicAdd(&gcnt[i * SUBS + sub], lc[i]);
}

// scan M = NB*SUBS counters; cursors line-padded (16 ints apart)
__global__ __launch_bounds__(1024) void k_bscan(const int* __restrict__ gcnt,
                                                int* __restrict__ boff,
                                                int* __restrict__ bnextp,
                                                int* __restrict__ offn, int M, int N) {
  __shared__ int s[1024];
  int t = threadIdx.x;
  int chunk = (M + 1023) / 1024;
  int lo = t * chunk; if (lo > M) lo = M;
  int hi = lo + chunk; if (hi > M) hi = M;
  int sum = 0;
  for (int i = lo; i < hi; ++i) sum += gcnt[i];
  s[t] = sum;
  __syncthreads();
  for (int d = 1; d < 1024; d <<= 1) {
    int v = (t >= d) ? s[t - d] : 0;
    __syncthreads();
    s[t] += v;
    __syncthreads();
  }
  int run = s[t] - sum;
  for (int i = lo; i < hi; ++i) {
    boff[i] = run;
    bnextp[(size_t)i * 16] = run;
    run += gcnt[i];
  }
  if (t == 1023) { boff[M] = s[1023]; offn[N] = s[1023]; }
}

// Tile-sorted scatter: one atomic per (tile,bucket); contiguous runs per bucket.
__global__ __launch_bounds__(256) void k_tscatter(const int* __restrict__ row,
                                                  const int* __restrict__ col,
                                                  const float* __restrict__ w,
                                                  int* __restrict__ bnextp,
                                                  int2* __restrict__ raw, int E, int NB) {
  __shared__ int lc[NBMAX];
  __shared__ int base[NBMAX];
  int t = threadIdx.x;
  for (int i = t; i < NB; i += 256) lc[i] = 0;
  __syncthreads();
  int e0 = blockIdx.x << TILE_SHIFT;
  int sub = blockIdx.x & (SUBS - 1);
  int e1 = e0 + (1 << TILE_SHIFT); if (e1 > E) e1 = E;
  for (int e = e0 + t; e < e1; e += 256) atomicAdd(&lc[col[e] >> 8], 1);
  __syncthreads();
  for (int i = t; i < NB; i += 256) {
    int c = lc[i];
    base[i] = c ? atomicAdd(&bnextp[(size_t)(i * SUBS + sub) * 16], c) : 0;
    lc[i] = 0;  // reuse as local cursor
  }
  __syncthreads();
  for (int e = e0 + t; e < e1; e += 256) {
    int c = col[e];
    int b = c >> 8;
    int p = base[b] + atomicAdd(&lc[b], 1);
    raw[p] = make_int2(row[e] | ((c & 255) << 20), __float_as_int(w[e]));
  }
}

// Per-bucket counting sort by local node id; emits offn[], dinv[], sorted edat.
__global__ __launch_bounds__(256) void k_bsort(const int2* __restrict__ raw,
                                               const int* __restrict__ boff,
                                               int2* __restrict__ edat,
                                               int* __restrict__ offn,
                                               float* __restrict__ dinv, int N) {
  __shared__ int cnt[256];
  __shared__ float wsum[256];
  __shared__ int s[256];
  __shared__ int pos[256];
  int t = threadIdx.x, b = blockIdx.x;
  int e0 = boff[b * SUBS], e1 = boff[(b + 1) * SUBS];
  cnt[t] = 0;
  wsum[t] = 0.0f;
  __syncthreads();
  for (int e = e0 + t; e < e1; e += 256) {
    int2 a = raw[e];
    int cl = ((unsigned)a.x) >> 20;
    atomicAdd(&cnt[cl], 1);
    atomicAdd(&wsum[cl], __int_as_float(a.y));
  }
  __syncthreads();
  int c = cnt[t];
  s[t] = c;
  __syncthreads();
  for (int d = 1; d < 256; d <<= 1) {
    int v = (t >= d) ? s[t - d] : 0;
    __syncthreads();
    s[t] += v;
    __syncthreads();
  }
  int excl = s[t] - c;
  int node = b * 256 + t;
  if (node < N) {
    dinv[node] = rsqrtf(wsum[t] + 1.0f);
    offn[node] = e0 + excl;
  }
  pos[t] = e0 + excl;
  __syncthreads();
  for (int e = e0 + t; e < e1; e += 256) {
    int2 a = raw[e];
    int p = atomicAdd(&pos[((unsigned)a.x) >> 20], 1);
    edat[p] = a;
  }
}

// Layer-1 aggregation on 6-wide features; 8 lanes/node; writes nrm into edat.y.
__global__ __launch_bounds__(256) void k_agg6(const float* __restrict__ vf,
                                              const float* __restrict__ dinv,
                                              const int* __restrict__ offn,
                                              int2* __restrict__ edat,
                                              float* __restrict__ Sx, int N) {
  int t = threadIdx.x, g = t >> 3, f = t & 7;
  int node = blockIdx.x * 32 + g;
  if (node >= N) return;
  bool act = f < 6;
  float dc = dinv[node];
  float acc = act ? dc * dc * vf[node * 6 + f] : 0.0f;
  int e1 = offn[node + 1];
  for (int e = offn[node]; e < e1; ++e) {
    int2 a = edat[e];
    int r = a.x & RMASK;
    float nrm = dinv[r] * __int_as_float(a.y) * dc;
    if (f == 0) edat[e].y = __float_as_int(nrm);
    if (act) acc += nrm * vf[r * 6 + f];
  }
  if (act) Sx[node * 6 + f] = acc;
}

// X = sigmoid(Sx @ W1 + b1), Sx [N,6], W1 [6,64]
__global__ __launch_bounds__(256) void k_gemm1(const float* __restrict__ Sx,
                                               const float* __restrict__ W1,
                                               const float* __restrict__ b1,
                                               float* __restrict__ X, int N) {
  __shared__ float Wl[6 * 64];
  __shared__ float bl[64];
  __shared__ float XT[6 * 65];
  int t = threadIdx.x;
  int n0 = blockIdx.x * 64;
  for (int i = t; i < 384; i += 256) {
    Wl[i] = W1[i];
    int n = i / 6, k = i - n * 6;
    int node = n0 + n;
    XT[k * 65 + n] = (node < N) ? Sx[node * 6 + k] : 0.0f;
  }
  if (t < 64) bl[t] = b1[t];
  __syncthreads();
  int c0 = (t & 15) * 4;
  int nn = (t >> 4) * 4;
  float acc[4][4];
#pragma unroll
  for (int i = 0; i < 4; ++i)
#pragma unroll
    for (int j = 0; j < 4; ++j) acc[i][j] = bl[c0 + j];
#pragma unroll
  for (int k = 0; k < 6; ++k) {
    float4 wv = *(const float4*)&Wl[k * 64 + c0];
    float xv[4];
#pragma unroll
    for (int i = 0; i < 4; ++i) xv[i] = XT[k * 65 + nn + i];
#pragma unroll
    for (int i = 0; i < 4; ++i) {
      acc[i][0] += xv[i] * wv.x;
      acc[i][1] += xv[i] * wv.y;
      acc[i][2] += xv[i] * wv.z;
      acc[i][3] += xv[i] * wv.w;
    }
  }
#pragma unroll
  for (int i = 0; i < 4; ++i) {
    int node = n0 + nn + i;
    if (node < N) {
      float4 o;
      o.x = sigf(acc[i][0]); o.y = sigf(acc[i][1]);
      o.z = sigf(acc[i][2]); o.w = sigf(acc[i][3]);
      *(float4*)&X[node * 64 + c0] = o;
    }
  }
}

// H(half) = X @ W  (X [N,64] f32, W [64,64] f32). 64x64 tile per block.
__global__ __launch_bounds__(256) void k_gemm64(const float* __restrict__ Xin,
                                                const float* __restrict__ W,
                                                __half* __restrict__ Hout, int N) {
  __shared__ float XT[64 * 65];
  __shared__ float Wl[64 * 64];
  int t = threadIdx.x;
  int n0 = blockIdx.x * 64;
#pragma unroll
  for (int i = 0; i < 4; ++i) {
    int idx = (i * 256 + t) * 4;
    *(float4*)&Wl[idx] = *(const float4*)&W[idx];
  }
#pragma unroll
  for (int i = 0; i < 4; ++i) {
    int idx = (i * 256 + t) * 4;
    int n = idx >> 6, k = idx & 63;
    int node = n0 + n;
    float4 xv = make_float4(0.f, 0.f, 0.f, 0.f);
    if (node < N) xv = *(const float4*)&Xin[node * 64 + k];
    XT[k * 65 + n] = xv.x;
    XT[(k + 1) * 65 + n] = xv.y;
    XT[(k + 2) * 65 + n] = xv.z;
    XT[(k + 3) * 65 + n] = xv.w;
  }
  __syncthreads();
  int c0 = (t & 15) * 4;
  int nn = (t >> 4) * 4;
  float acc[4][4] = {{0.f}};
#pragma unroll
  for (int k = 0; k < 64; ++k) {
    float4 wv = *(const float4*)&Wl[k * 64 + c0];
    float xv[4];
#pragma unroll
    for (int i = 0; i < 4; ++i) xv[i] = XT[k * 65 + nn + i];
#pragma unroll
    for (int i = 0; i < 4; ++i) {
      acc[i][0] += xv[i] * wv.x;
      acc[i][1] += xv[i] * wv.y;
      acc[i][2] += xv[i] * wv.z;
      acc[i][3] += xv[i] * wv.w;
    }
  }
#pragma unroll
  for (int i = 0; i < 4; ++i) {
    int node = n0 + nn + i;
    if (node < N) {
      __half2 h01 = __floats2half2_rn(acc[i][0], acc[i][1]);
      __half2 h23 = __floats2half2_rn(acc[i][2], acc[i][3]);
      __half2* dst = (__half2*)(Hout + (size_t)node * 64 + c0);
      dst[0] = h01;
      dst[1] = h23;
    }
  }
}

// Half-wave-per-node CSC gather agg on fp16 H; lane owns features {2l,2l+1}.
// LAST: fuse W5 dot -> h5.
template <bool LAST>
__global__ __launch_bounds__(256) void k_agg64(const __half* __restrict__ Hin,
                                               const float* __restrict__ dinv,
                                               const int* __restrict__ offn,
                                               const int2* __restrict__ edat,
                                               const float* __restrict__ b,
                                               const float* __restrict__ W5,
                                               float* __restrict__ Xout,
                                               float* __restrict__ h5, int N) {
  const __half2* Hh = (const __half2*)Hin;  // [N][32] half2
  int t = threadIdx.x;
  int l = t & 31;           // half-wave lane: feature pair index
  int hw = t >> 5;          // 8 half-waves per block
  int node = blockIdx.x * 8 + hw;
  if (node >= N) return;
  float di = dinv[node];
  float2 sf = __half22float2(Hh[(size_t)node * 32 + l]);
  float2 acc = make_float2(di * di * sf.x, di * di * sf.y);
  int e = offn[node], e1 = offn[node + 1];
  for (; e + 3 < e1; e += 4) {
    int2 a0 = edat[e];
    int2 a1 = edat[e + 1];
    int2 a2 = edat[e + 2];
    int2 a3 = edat[e + 3];
    float2 h0 = __half22float2(Hh[(size_t)(a0.x & RMASK) * 32 + l]);
    float2 h1 = __half22float2(Hh[(size_t)(a1.x & RMASK) * 32 + l]);
    float2 h2 = __half22float2(Hh[(size_t)(a2.x & RMASK) * 32 + l]);
    float2 h3 = __half22float2(Hh[(size_t)(a3.x & RMASK) * 32 + l]);
    float n0 = __int_as_float(a0.y), n1 = __int_as_float(a1.y);
    float n2 = __int_as_float(a2.y), n3 = __int_as_float(a3.y);
    acc.x += n0 * h0.x + n1 * h1.x + n2 * h2.x + n3 * h3.x;
    acc.y += n0 * h0.y + n1 * h1.y + n2 * h2.y + n3 * h3.y;
  }
  for (; e < e1; ++e) {
    int2 a = edat[e];
    float2 hv = __half22float2(Hh[(size_t)(a.x & RMASK) * 32 + l]);
    float nm = __int_as_float(a.y);
    acc.x += nm * hv.x;
    acc.y += nm * hv.y;
  }
  float2 bb = ((const float2*)b)[l];
  float x0 = sigf(acc.x + bb.x);
  float x1 = sigf(acc.y + bb.y);
  if (LAST) {
    float2 w5 = ((const float2*)W5)[l];
    float v = x0 * w5.x + x1 * w5.y;
#pragma unroll
    for (int d = 16; d; d >>= 1) v += __shfl_xor(v, d);  // within half-wave
    if (l == 0) h5[node] = v;
  } else {
    ((float2*)(Xout + (size_t)node * 64))[l] = make_float2(x0, x1);
  }
}

// scalar CSC aggregation + sigmoid + per-block partial sum
__global__ __launch_bounds__(256) void k_agg5(const float* __restrict__ h5,
                                              const float* __restrict__ dinv,
                                              const int* __restrict__ offn,
                                              const int2* __restrict__ edat,
                                              const float* __restrict__ b5,
                                              float* __restrict__ partials, int N) {
  int n = blockIdx.x * 256 + threadIdx.x;
  float sig = 0.0f;
  if (n < N) {
    float di = dinv[n];
    float acc = di * di * h5[n];
    int e1 = offn[n + 1];
    for (int e = offn[n]; e < e1; ++e) {
      int2 a = edat[e];
      acc += __int_as_float(a.y) * h5[a.x & RMASK];
    }
    sig = sigf(acc + b5[0]);
  }
#pragma unroll
  for (int d = 32; d; d >>= 1) sig += __shfl_xor(sig, d);
  __shared__ float ws[4];
  int lane = threadIdx.x & 63, wid = threadIdx.x >> 6;
  if (lane == 0) ws[wid] = sig;
  __syncthreads();
  if (threadIdx.x == 0) partials[blockIdx.x] = ws[0] + ws[1] + ws[2] + ws[3];
}

__global__ __launch_bounds__(512) void k_final(const float* __restrict__ partials,
                                               float* __restrict__ out, int nb,
                                               float invN) {
  float v = 0.0f;
  for (int i = threadIdx.x; i < nb; i += 512) v += partials[i];
#pragma unroll
  for (int d = 32; d; d >>= 1) v += __shfl_xor(v, d);
  __shared__ float ws[8];
  int lane = threadIdx.x & 63, wid = threadIdx.x >> 6;
  if (lane == 0) ws[wid] = v;
  __syncthreads();
  if (threadIdx.x == 0) {
    float s = 0.0f;
    for (int i = 0; i < 8; ++i) s += ws[i];
    out[0] = s * invN;
  }
}

extern "C" void kernel_launch(void* const* d_in, const int* in_sizes, int n_in,
                              void* d_out, int out_size, void* d_ws, size_t ws_size,
                              hipStream_t stream) {
  const float* vf = (const float*)d_in[0];
  const int* edges = (const int*)d_in[1];
  const float* w = (const float*)d_in[2];
  const float* W1 = (const float*)d_in[3];
  const float* b1 = (const float*)d_in[4];
  const float* W2 = (const float*)d_in[5];
  const float* b2 = (const float*)d_in[6];
  const float* W3 = (const float*)d_in[7];
  const float* b3 = (const float*)d_in[8];
  const float* W4 = (const float*)d_in[9];
  const float* b4 = (const float*)d_in[10];
  const float* W5 = (const float*)d_in[11];
  const float* b5 = (const float*)d_in[12];
  float* out = (float*)d_out;

  const int N = in_sizes[0] / 6;
  const int E = in_sizes[2];
  const int* row = edges;
  const int* col = edges + E;
  const int NB = (N + 255) >> 8;
  const int M = NB * SUBS;

  size_t o = 0;
  auto carve = [&](size_t bytes) -> void* {
    void* p = (char*)d_ws + o;
    o += (bytes + 255) & ~(size_t)255;
    return p;
  };
  float* X = (float*)carve((size_t)N * 64 * 4);
  size_t hbytes = (size_t)N * 64 * 2;  // fp16 H
  size_t rbytes = (size_t)E * 8;
  __half* H = (__half*)carve(hbytes > rbytes ? hbytes : rbytes);  // raw overlays H
  int2* raw = (int2*)H;
  int2* edat = (int2*)carve((size_t)E * 8);
  float* Sx = (float*)carve((size_t)N * 6 * 4);
  float* dinv = (float*)carve((size_t)N * 4);
  int* boff = (int*)carve((size_t)(M + 1) * 4);
  int* bnextp = (int*)carve((size_t)M * 16 * 4);  // line-padded cursors
  int* gcnt = (int*)carve((size_t)M * 4);
  int* offn = (int*)carve((size_t)(N + 1) * 4);
  float* h5 = (float*)carve((size_t)N * 4);
  const int nb5 = (N + 255) / 256;
  float* partials = (float*)carve((size_t)nb5 * 4);

  hipMemsetAsync(gcnt, 0, (size_t)M * 4, stream);

  const int tiles = (E + (1 << TILE_SHIFT) - 1) >> TILE_SHIFT;
  k_count<<<tiles, 256, 0, stream>>>(col, gcnt, E, NB);
  k_bscan<<<1, 1024, 0, stream>>>(gcnt, boff, bnextp, offn, M, N);
  k_tscatter<<<tiles, 256, 0, stream>>>(row, col, w, bnextp, raw, E, NB);
  k_bsort<<<NB, 256, 0, stream>>>(raw, boff, edat, offn, dinv, N);

  // layer 1: aggregate features (D=6) + compute/store nrm, then dense 6->64
  k_agg6<<<(N + 31) / 32, 256, 0, stream>>>(vf, dinv, offn, edat, Sx, N);
  k_gemm1<<<(N + 63) / 64, 256, 0, stream>>>(Sx, W1, b1, X, N);

  // layers 2-4 (H overwrites raw, which is fully consumed by k_bsort)
  const int nbA = (N + 7) / 8;
  k_gemm64<<<(N + 63) / 64, 256, 0, stream>>>(X, W2, H, N);
  k_agg64<false><<<nbA, 256, 0, stream>>>(H, dinv, offn, edat, b2, W5, X, h5, N);
  k_gemm64<<<(N + 63) / 64, 256, 0, stream>>>(X, W3, H, N);
  k_agg64<false><<<nbA, 256, 0, stream>>>(H, dinv, offn, edat, b3, W5, X, h5, N);
  k_gemm64<<<(N + 63) / 64, 256, 0, stream>>>(X, W4, H, N);
  k_agg64<true><<<nbA, 256, 0, stream>>>(H, dinv, offn, edat, b4, W5, X, h5, N);

  // layer 5: scalar aggregation + mean
  k_agg5<<<nb5, 256, 0, stream>>>(h5, dinv, offn, edat, b5, partials, N);
  k_final<<<1, 512, 0, stream>>>(partials, out, nb5, 1.0f / (float)N);
}

// Round 12
// 575.024 us; speedup vs baseline: 9.6203x; 1.0461x over previous
//
#include <hip/hip_runtime.h>
#include <hip/hip_fp16.h>
#include <math.h>

// GCN 5-layer on MI355X — round 12:
//  (a) nrm fused into CSC build: k_bsort split into bsort1 (offn/dinv) and
//      bsort2 (scatter {r|cl, nrm} with full 8B stores) -> k_agg6 becomes
//      read-only (kills its 82MB partial-line write amplification).
//  (b) fp16 X everywhere (gemm1/agg64 store half, gemm64 reads half) —
//      halves the X streams in 4 kernels, same as the measured fp16-H win.
// Rest as R11 (measured-good): tile-sorted scatter, fp16 H, CSC gather agg.

__device__ __forceinline__ float sigf(float x) { return 1.0f / (1.0f + expf(-x)); }

#define RMASK 0xFFFFF
#define SUBS 8            // cursor streams per bucket (blockIdx & 7)
#define TILE_SHIFT 13     // 8192 edges per tile
#define NBMAX 512

__global__ __launch_bounds__(256) void k_count(const int* __restrict__ col,
                                               int* __restrict__ gcnt, int E, int NB) {
  __shared__ int lc[NBMAX];
  int t = threadIdx.x;
  for (int i = t; i < NB; i += 256) lc[i] = 0;
  __syncthreads();
  int base = blockIdx.x << TILE_SHIFT;
  int sub = blockIdx.x & (SUBS - 1);
  int hi = base + (1 << TILE_SHIFT); if (hi > E) hi = E;
  for (int e = base + t; e < hi; e += 256) atomicAdd(&lc[col[e] >> 8], 1);
  __syncthreads();
  for (int i = t; i < NB; i += 256)
    if (lc[i]) atomicAdd(&gcnt[i * SUBS + sub], lc[i]);
}

// scan M = NB*SUBS counters; cursors line-padded (16 ints apart)
__global__ __launch_bounds__(1024) void k_bscan(const int* __restrict__ gcnt,
                                                int* __restrict__ boff,
                                                int* __restrict__ bnextp,
                                                int* __restrict__ offn, int M, int N) {
  __shared__ int s[1024];
  int t = threadIdx.x;
  int chunk = (M + 1023) / 1024;
  int lo = t * chunk; if (lo > M) lo = M;
  int hi = lo + chunk; if (hi > M) hi = M;
  int sum = 0;
  for (int i = lo; i < hi; ++i) sum += gcnt[i];
  s[t] = sum;
  __syncthreads();
  for (int d = 1; d < 1024; d <<= 1) {
    int v = (t >= d) ? s[t - d] : 0;
    __syncthreads();
    s[t] += v;
    __syncthreads();
  }
  int run = s[t] - sum;
  for (int i = lo; i < hi; ++i) {
    boff[i] = run;
    bnextp[(size_t)i * 16] = run;
    run += gcnt[i];
  }
  if (t == 1023) { boff[M] = s[1023]; offn[N] = s[1023]; }
}

// Tile-sorted scatter: one atomic per (tile,bucket); contiguous runs per bucket.
__global__ __launch_bounds__(256) void k_tscatter(const int* __restrict__ row,
                                                  const int* __restrict__ col,
                                                  const float* __restrict__ w,
                                                  int* __restrict__ bnextp,
                                                  int2* __restrict__ raw, int E, int NB) {
  __shared__ int lc[NBMAX];
  __shared__ int base[NBMAX];
  int t = threadIdx.x;
  for (int i = t; i < NB; i += 256) lc[i] = 0;
  __syncthreads();
  int e0 = blockIdx.x << TILE_SHIFT;
  int sub = blockIdx.x & (SUBS - 1);
  int e1 = e0 + (1 << TILE_SHIFT); if (e1 > E) e1 = E;
  for (int e = e0 + t; e < e1; e += 256) atomicAdd(&lc[col[e] >> 8], 1);
  __syncthreads();
  for (int i = t; i < NB; i += 256) {
    int c = lc[i];
    base[i] = c ? atomicAdd(&bnextp[(size_t)(i * SUBS + sub) * 16], c) : 0;
    lc[i] = 0;  // reuse as local cursor
  }
  __syncthreads();
  for (int e = e0 + t; e < e1; e += 256) {
    int c = col[e];
    int b = c >> 8;
    int p = base[b] + atomicAdd(&lc[b], 1);
    raw[p] = make_int2(row[e] | ((c & 255) << 20), __float_as_int(w[e]));
  }
}

// Pass 1: per-bucket histogram+wsum+scan -> offn[], dinv[]. No scatter.
__global__ __launch_bounds__(256) void k_bsort1(const int2* __restrict__ raw,
                                                const int* __restrict__ boff,
                                                int* __restrict__ offn,
                                                float* __restrict__ dinv, int N) {
  __shared__ int cnt[256];
  __shared__ float wsum[256];
  __shared__ int s[256];
  int t = threadIdx.x, b = blockIdx.x;
  int e0 = boff[b * SUBS], e1 = boff[(b + 1) * SUBS];
  cnt[t] = 0;
  wsum[t] = 0.0f;
  __syncthreads();
  for (int e = e0 + t; e < e1; e += 256) {
    int2 a = raw[e];
    int cl = ((unsigned)a.x) >> 20;
    atomicAdd(&cnt[cl], 1);
    atomicAdd(&wsum[cl], __int_as_float(a.y));
  }
  __syncthreads();
  int c = cnt[t];
  s[t] = c;
  __syncthreads();
  for (int d = 1; d < 256; d <<= 1) {
    int v = (t >= d) ? s[t - d] : 0;
    __syncthreads();
    s[t] += v;
    __syncthreads();
  }
  int node = b * 256 + t;
  if (node < N) {
    dinv[node] = rsqrtf(wsum[t] + 1.0f);
    offn[node] = e0 + (s[t] - c);
  }
}

// Pass 2 (after global barrier: all dinv ready): scatter sorted edges with nrm.
__global__ __launch_bounds__(256) void k_bsort2(const int2* __restrict__ raw,
                                                const int* __restrict__ boff,
                                                const int* __restrict__ offn,
                                                const float* __restrict__ dinv,
                                                int2* __restrict__ edat, int N) {
  __shared__ int pos[256];
  __shared__ float dl[256];
  int t = threadIdx.x, b = blockIdx.x;
  int e0 = boff[b * SUBS], e1 = boff[(b + 1) * SUBS];
  int node = b * 256 + t;
  pos[t] = (node < N) ? offn[node] : 0;
  dl[t] = (node < N) ? dinv[node] : 0.0f;
  __syncthreads();
  for (int e = e0 + t; e < e1; e += 256) {
    int2 a = raw[e];
    int r = a.x & RMASK;
    int cl = ((unsigned)a.x) >> 20;
    float nrm = dinv[r] * __int_as_float(a.y) * dl[cl];
    int p = atomicAdd(&pos[cl], 1);
    edat[p] = make_int2(a.x, __float_as_int(nrm));
  }
}

// Layer-1 aggregation on 6-wide features; 8 lanes/node; read-only now.
__global__ __launch_bounds__(256) void k_agg6(const float* __restrict__ vf,
                                              const float* __restrict__ dinv,
                                              const int* __restrict__ offn,
                                              const int2* __restrict__ edat,
                                              float* __restrict__ Sx, int N) {
  int t = threadIdx.x, g = t >> 3, f = t & 7;
  int node = blockIdx.x * 32 + g;
  if (node >= N) return;
  bool act = f < 6;
  float dc = dinv[node];
  float acc = act ? dc * dc * vf[node * 6 + f] : 0.0f;
  int e1 = offn[node + 1];
  for (int e = offn[node]; e < e1; ++e) {
    int2 a = edat[e];
    if (act) acc += __int_as_float(a.y) * vf[(a.x & RMASK) * 6 + f];
  }
  if (act) Sx[node * 6 + f] = acc;
}

// X(half) = sigmoid(Sx @ W1 + b1), Sx [N,6], W1 [6,64]
__global__ __launch_bounds__(256) void k_gemm1(const float* __restrict__ Sx,
                                               const float* __restrict__ W1,
                                               const float* __restrict__ b1,
                                               __half* __restrict__ X, int N) {
  __shared__ float Wl[6 * 64];
  __shared__ float bl[64];
  __shared__ float XT[6 * 65];
  int t = threadIdx.x;
  int n0 = blockIdx.x * 64;
  for (int i = t; i < 384; i += 256) {
    Wl[i] = W1[i];
    int n = i / 6, k = i - n * 6;
    int node = n0 + n;
    XT[k * 65 + n] = (node < N) ? Sx[node * 6 + k] : 0.0f;
  }
  if (t < 64) bl[t] = b1[t];
  __syncthreads();
  int c0 = (t & 15) * 4;
  int nn = (t >> 4) * 4;
  float acc[4][4];
#pragma unroll
  for (int i = 0; i < 4; ++i)
#pragma unroll
    for (int j = 0; j < 4; ++j) acc[i][j] = bl[c0 + j];
#pragma unroll
  for (int k = 0; k < 6; ++k) {
    float4 wv = *(const float4*)&Wl[k * 64 + c0];
    float xv[4];
#pragma unroll
    for (int i = 0; i < 4; ++i) xv[i] = XT[k * 65 + nn + i];
#pragma unroll
    for (int i = 0; i < 4; ++i) {
      acc[i][0] += xv[i] * wv.x;
      acc[i][1] += xv[i] * wv.y;
      acc[i][2] += xv[i] * wv.z;
      acc[i][3] += xv[i] * wv.w;
    }
  }
#pragma unroll
  for (int i = 0; i < 4; ++i) {
    int node = n0 + nn + i;
    if (node < N) {
      __half2* dst = (__half2*)(X + (size_t)node * 64 + c0);
      dst[0] = __floats2half2_rn(sigf(acc[i][0]), sigf(acc[i][1]));
      dst[1] = __floats2half2_rn(sigf(acc[i][2]), sigf(acc[i][3]));
    }
  }
}

// H(half) = X(half) @ W(f32). 64x64 tile per block.
__global__ __launch_bounds__(256) void k_gemm64(const __half* __restrict__ Xin,
                                                const float* __restrict__ W,
                                                __half* __restrict__ Hout, int N) {
  __shared__ float XT[64 * 65];
  __shared__ float Wl[64 * 64];
  int t = threadIdx.x;
  int n0 = blockIdx.x * 64;
#pragma unroll
  for (int i = 0; i < 4; ++i) {
    int idx = (i * 256 + t) * 4;
    *(float4*)&Wl[idx] = *(const float4*)&W[idx];
  }
#pragma unroll
  for (int i = 0; i < 2; ++i) {
    int idx = (i * 256 + t) * 8;
    int n = idx >> 6, k = idx & 63;
    int node = n0 + n;
    __half2 hv[4];
    if (node < N) {
      const __half2* src = (const __half2*)(Xin + (size_t)node * 64 + k);
      hv[0] = src[0]; hv[1] = src[1]; hv[2] = src[2]; hv[3] = src[3];
    } else {
      hv[0] = hv[1] = hv[2] = hv[3] = __floats2half2_rn(0.f, 0.f);
    }
#pragma unroll
    for (int j = 0; j < 4; ++j) {
      float2 f = __half22float2(hv[j]);
      XT[(k + 2 * j) * 65 + n] = f.x;
      XT[(k + 2 * j + 1) * 65 + n] = f.y;
    }
  }
  __syncthreads();
  int c0 = (t & 15) * 4;
  int nn = (t >> 4) * 4;
  float acc[4][4] = {{0.f}};
#pragma unroll
  for (int k = 0; k < 64; ++k) {
    float4 wv = *(const float4*)&Wl[k * 64 + c0];
    float xv[4];
#pragma unroll
    for (int i = 0; i < 4; ++i) xv[i] = XT[k * 65 + nn + i];
#pragma unroll
    for (int i = 0; i < 4; ++i) {
      acc[i][0] += xv[i] * wv.x;
      acc[i][1] += xv[i] * wv.y;
      acc[i][2] += xv[i] * wv.z;
      acc[i][3] += xv[i] * wv.w;
    }
  }
#pragma unroll
  for (int i = 0; i < 4; ++i) {
    int node = n0 + nn + i;
    if (node < N) {
      __half2* dst = (__half2*)(Hout + (size_t)node * 64 + c0);
      dst[0] = __floats2half2_rn(acc[i][0], acc[i][1]);
      dst[1] = __floats2half2_rn(acc[i][2], acc[i][3]);
    }
  }
}

// Half-wave-per-node CSC gather agg on fp16 H; lane owns features {2l,2l+1}.
// LAST: fuse W5 dot -> h5 (f32 out); else write fp16 X.
template <bool LAST>
__global__ __launch_bounds__(256) void k_agg64(const __half* __restrict__ Hin,
                                               const float* __restrict__ dinv,
                                               const int* __restrict__ offn,
                                               const int2* __restrict__ edat,
                                               const float* __restrict__ b,
                                               const float* __restrict__ W5,
                                               __half* __restrict__ Xout,
                                               float* __restrict__ h5, int N) {
  const __half2* Hh = (const __half2*)Hin;  // [N][32] half2
  int t = threadIdx.x;
  int l = t & 31;           // half-wave lane: feature pair index
  int hw = t >> 5;          // 8 half-waves per block
  int node = blockIdx.x * 8 + hw;
  if (node >= N) return;
  float di = dinv[node];
  float2 sf = __half22float2(Hh[(size_t)node * 32 + l]);
  float2 acc = make_float2(di * di * sf.x, di * di * sf.y);
  int e = offn[node], e1 = offn[node + 1];
  for (; e + 3 < e1; e += 4) {
    int2 a0 = edat[e];
    int2 a1 = edat[e + 1];
    int2 a2 = edat[e + 2];
    int2 a3 = edat[e + 3];
    float2 h0 = __half22float2(Hh[(size_t)(a0.x & RMASK) * 32 + l]);
    float2 h1 = __half22float2(Hh[(size_t)(a1.x & RMASK) * 32 + l]);
    float2 h2 = __half22float2(Hh[(size_t)(a2.x & RMASK) * 32 + l]);
    float2 h3 = __half22float2(Hh[(size_t)(a3.x & RMASK) * 32 + l]);
    float n0 = __int_as_float(a0.y), n1 = __int_as_float(a1.y);
    float n2 = __int_as_float(a2.y), n3 = __int_as_float(a3.y);
    acc.x += n0 * h0.x + n1 * h1.x + n2 * h2.x + n3 * h3.x;
    acc.y += n0 * h0.y + n1 * h1.y + n2 * h2.y + n3 * h3.y;
  }
  for (; e < e1; ++e) {
    int2 a = edat[e];
    float2 hv = __half22float2(Hh[(size_t)(a.x & RMASK) * 32 + l]);
    float nm = __int_as_float(a.y);
    acc.x += nm * hv.x;
    acc.y += nm * hv.y;
  }
  float2 bb = ((const float2*)b)[l];
  float x0 = sigf(acc.x + bb.x);
  float x1 = sigf(acc.y + bb.y);
  if (LAST) {
    float2 w5 = ((const float2*)W5)[l];
    float v = x0 * w5.x + x1 * w5.y;
#pragma unroll
    for (int d = 16; d; d >>= 1) v += __shfl_xor(v, d);  // within half-wave
    if (l == 0) h5[node] = v;
  } else {
    ((__half2*)(Xout + (size_t)node * 64))[l] = __floats2half2_rn(x0, x1);
  }
}

// scalar CSC aggregation + sigmoid + per-block partial sum
__global__ __launch_bounds__(256) void k_agg5(const float* __restrict__ h5,
                                              const float* __restrict__ dinv,
                                              const int* __restrict__ offn,
                                              const int2* __restrict__ edat,
                                              const float* __restrict__ b5,
                                              float* __restrict__ partials, int N) {
  int n = blockIdx.x * 256 + threadIdx.x;
  float sig = 0.0f;
  if (n < N) {
    float di = dinv[n];
    float acc = di * di * h5[n];
    int e1 = offn[n + 1];
    for (int e = offn[n]; e < e1; ++e) {
      int2 a = edat[e];
      acc += __int_as_float(a.y) * h5[a.x & RMASK];
    }
    sig = sigf(acc + b5[0]);
  }
#pragma unroll
  for (int d = 32; d; d >>= 1) sig += __shfl_xor(sig, d);
  __shared__ float ws[4];
  int lane = threadIdx.x & 63, wid = threadIdx.x >> 6;
  if (lane == 0) ws[wid] = sig;
  __syncthreads();
  if (threadIdx.x == 0) partials[blockIdx.x] = ws[0] + ws[1] + ws[2] + ws[3];
}

__global__ __launch_bounds__(512) void k_final(const float* __restrict__ partials,
                                               float* __restrict__ out, int nb,
                                               float invN) {
  float v = 0.0f;
  for (int i = threadIdx.x; i < nb; i += 512) v += partials[i];
#pragma unroll
  for (int d = 32; d; d >>= 1) v += __shfl_xor(v, d);
  __shared__ float ws[8];
  int lane = threadIdx.x & 63, wid = threadIdx.x >> 6;
  if (lane == 0) ws[wid] = v;
  __syncthreads();
  if (threadIdx.x == 0) {
    float s = 0.0f;
    for (int i = 0; i < 8; ++i) s += ws[i];
    out[0] = s * invN;
  }
}

extern "C" void kernel_launch(void* const* d_in, const int* in_sizes, int n_in,
                              void* d_out, int out_size, void* d_ws, size_t ws_size,
                              hipStream_t stream) {
  const float* vf = (const float*)d_in[0];
  const int* edges = (const int*)d_in[1];
  const float* w = (const float*)d_in[2];
  const float* W1 = (const float*)d_in[3];
  const float* b1 = (const float*)d_in[4];
  const float* W2 = (const float*)d_in[5];
  const float* b2 = (const float*)d_in[6];
  const float* W3 = (const float*)d_in[7];
  const float* b3 = (const float*)d_in[8];
  const float* W4 = (const float*)d_in[9];
  const float* b4 = (const float*)d_in[10];
  const float* W5 = (const float*)d_in[11];
  const float* b5 = (const float*)d_in[12];
  float* out = (float*)d_out;

  const int N = in_sizes[0] / 6;
  const int E = in_sizes[2];
  const int* row = edges;
  const int* col = edges + E;
  const int NB = (N + 255) >> 8;
  const int M = NB * SUBS;

  size_t o = 0;
  auto carve = [&](size_t bytes) -> void* {
    void* p = (char*)d_ws + o;
    o += (bytes + 255) & ~(size_t)255;
    return p;
  };
  __half* X = (__half*)carve((size_t)N * 64 * 2);
  size_t hbytes = (size_t)N * 64 * 2;  // fp16 H
  size_t rbytes = (size_t)E * 8;
  __half* H = (__half*)carve(hbytes > rbytes ? hbytes : rbytes);  // raw overlays H
  int2* raw = (int2*)H;
  int2* edat = (int2*)carve((size_t)E * 8);
  float* Sx = (float*)carve((size_t)N * 6 * 4);
  float* dinv = (float*)carve((size_t)N * 4);
  int* boff = (int*)carve((size_t)(M + 1) * 4);
  int* bnextp = (int*)carve((size_t)M * 16 * 4);  // line-padded cursors
  int* gcnt = (int*)carve((size_t)M * 4);
  int* offn = (int*)carve((size_t)(N + 1) * 4);
  float* h5 = (float*)carve((size_t)N * 4);
  const int nb5 = (N + 255) / 256;
  float* partials = (float*)carve((size_t)nb5 * 4);

  hipMemsetAsync(gcnt, 0, (size_t)M * 4, stream);

  const int tiles = (E + (1 << TILE_SHIFT) - 1) >> TILE_SHIFT;
  k_count<<<tiles, 256, 0, stream>>>(col, gcnt, E, NB);
  k_bscan<<<1, 1024, 0, stream>>>(gcnt, boff, bnextp, offn, M, N);
  k_tscatter<<<tiles, 256, 0, stream>>>(row, col, w, bnextp, raw, E, NB);
  k_bsort1<<<NB, 256, 0, stream>>>(raw, boff, offn, dinv, N);
  k_bsort2<<<NB, 256, 0, stream>>>(raw, boff, offn, dinv, edat, N);

  // layer 1: aggregate features (D=6), then dense 6->64 (fp16 X out)
  k_agg6<<<(N + 31) / 32, 256, 0, stream>>>(vf, dinv, offn, edat, Sx, N);
  k_gemm1<<<(N + 63) / 64, 256, 0, stream>>>(Sx, W1, b1, X, N);

  // layers 2-4 (H overwrites raw, which is fully consumed by k_bsort2)
  const int nbA = (N + 7) / 8;
  k_gemm64<<<(N + 63) / 64, 256, 0, stream>>>(X, W2, H, N);
  k_agg64<false><<<nbA, 256, 0, stream>>>(H, dinv, offn, edat, b2, W5, X, h5, N);
  k_gemm64<<<(N + 63) / 64, 256, 0, stream>>>(X, W3, H, N);
  k_agg64<false><<<nbA, 256, 0, stream>>>(H, dinv, offn, edat, b3, W5, X, h5, N);
  k_gemm64<<<(N + 63) / 64, 256, 0, stream>>>(X, W4, H, N);
  k_agg64<true><<<nbA, 256, 0, stream>>>(H, dinv, offn, edat, b4, W5, X, h5, N);

  // layer 5: scalar aggregation + mean
  k_agg5<<<nb5, 256, 0, stream>>>(h5, dinv, offn, edat, b5, partials, N);
  k_final<<<1, 512, 0, stream>>>(partials, out, nb5, 1.0f / (float)N);
}

// Round 13
// 560.693 us; speedup vs baseline: 9.8662x; 1.0256x over previous
//
#include <hip/hip_runtime.h>
#include <hip/hip_fp16.h>
#include <math.h>

// GCN 5-layer on MI355X — round 13: eliminate bsort2 by algebra.
// nrm = dinv[r]*w*dinv[c] is split: edat.y = w*dinv[c] (bucket-local, single
// merged k_bsort), and dinv[r] is folded into the gathered operand at its
// generation point: H' = dinv.*(X@W) (gemm64 epilogue), vfs = dinv.*vf
// (k_scale), h5' = dinv.*h5 (agg64-LAST epilogue). Aggregations become
// sum(edat.y * op'[r]) + dinv[c]*op'[c]  — algebraically identical.
// Also: k_count saves per-tile histograms so k_tscatter skips re-histogram.
// Measured-good parts kept: tile-sorted scatter, fp16 H/X, CSC gather agg.

__device__ __forceinline__ float sigf(float x) { return 1.0f / (1.0f + expf(-x)); }

#define RMASK 0xFFFFF
#define SUBS 8            // cursor streams per bucket (blockIdx & 7)
#define TILE_SHIFT 13     // 8192 edges per tile
#define NBMAX 512

__global__ __launch_bounds__(256) void k_count(const int* __restrict__ col,
                                               int* __restrict__ gcnt,
                                               int* __restrict__ gtile, int E, int NB) {
  __shared__ int lc[NBMAX];
  int t = threadIdx.x;
  for (int i = t; i < NB; i += 256) lc[i] = 0;
  __syncthreads();
  int base = blockIdx.x << TILE_SHIFT;
  int sub = blockIdx.x & (SUBS - 1);
  int hi = base + (1 << TILE_SHIFT); if (hi > E) hi = E;
  for (int e = base + t; e < hi; e += 256) atomicAdd(&lc[col[e] >> 8], 1);
  __syncthreads();
  size_t gt = (size_t)blockIdx.x * NB;
  for (int i = t; i < NB; i += 256) {
    int c = lc[i];
    gtile[gt + i] = c;
    if (c) atomicAdd(&gcnt[i * SUBS + sub], c);
  }
}

// scan M = NB*SUBS counters; cursors line-padded (16 ints apart)
__global__ __launch_bounds__(1024) void k_bscan(const int* __restrict__ gcnt,
                                                int* __restrict__ boff,
                                                int* __restrict__ bnextp,
                                                int* __restrict__ offn, int M, int N) {
  __shared__ int s[1024];
  int t = threadIdx.x;
  int chunk = (M + 1023) / 1024;
  int lo = t * chunk; if (lo > M) lo = M;
  int hi = lo + chunk; if (hi > M) hi = M;
  int sum = 0;
  for (int i = lo; i < hi; ++i) sum += gcnt[i];
  s[t] = sum;
  __syncthreads();
  for (int d = 1; d < 1024; d <<= 1) {
    int v = (t >= d) ? s[t - d] : 0;
    __syncthreads();
    s[t] += v;
    __syncthreads();
  }
  int run = s[t] - sum;
  for (int i = lo; i < hi; ++i) {
    boff[i] = run;
    bnextp[(size_t)i * 16] = run;
    run += gcnt[i];
  }
  if (t == 1023) { boff[M] = s[1023]; offn[N] = s[1023]; }
}

// Tile-sorted scatter: histogram read from gtile; one atomic per (tile,bucket).
__global__ __launch_bounds__(256) void k_tscatter(const int* __restrict__ row,
                                                  const int* __restrict__ col,
                                                  const float* __restrict__ w,
                                                  const int* __restrict__ gtile,
                                                  int* __restrict__ bnextp,
                                                  int2* __restrict__ raw, int E, int NB) {
  __shared__ int lc[NBMAX];
  __shared__ int base[NBMAX];
  int t = threadIdx.x;
  int e0 = blockIdx.x << TILE_SHIFT;
  int sub = blockIdx.x & (SUBS - 1);
  int e1 = e0 + (1 << TILE_SHIFT); if (e1 > E) e1 = E;
  size_t gt = (size_t)blockIdx.x * NB;
  for (int i = t; i < NB; i += 256) {
    int c = gtile[gt + i];
    base[i] = c ? atomicAdd(&bnextp[(size_t)(i * SUBS + sub) * 16], c) : 0;
    lc[i] = 0;
  }
  __syncthreads();
  for (int e = e0 + t; e < e1; e += 256) {
    int c = col[e];
    int b = c >> 8;
    int p = base[b] + atomicAdd(&lc[b], 1);
    raw[p] = make_int2(row[e] | ((c & 255) << 20), __float_as_int(w[e]));
  }
}

// Merged per-bucket counting sort: offn/dinv + scatter edat.y = w*dinv[c].
__global__ __launch_bounds__(256) void k_bsort(const int2* __restrict__ raw,
                                               const int* __restrict__ boff,
                                               int2* __restrict__ edat,
                                               int* __restrict__ offn,
                                               float* __restrict__ dinv, int N) {
  __shared__ int cnt[256];
  __shared__ float wsum[256];
  __shared__ int s[256];
  __shared__ int pos[256];
  __shared__ float dl[256];
  int t = threadIdx.x, b = blockIdx.x;
  int e0 = boff[b * SUBS], e1 = boff[(b + 1) * SUBS];
  cnt[t] = 0;
  wsum[t] = 0.0f;
  __syncthreads();
  for (int e = e0 + t; e < e1; e += 256) {
    int2 a = raw[e];
    int cl = ((unsigned)a.x) >> 20;
    atomicAdd(&cnt[cl], 1);
    atomicAdd(&wsum[cl], __int_as_float(a.y));
  }
  __syncthreads();
  int c = cnt[t];
  s[t] = c;
  __syncthreads();
  for (int d = 1; d < 256; d <<= 1) {
    int v = (t >= d) ? s[t - d] : 0;
    __syncthreads();
    s[t] += v;
    __syncthreads();
  }
  int excl = s[t] - c;
  float dv = rsqrtf(wsum[t] + 1.0f);
  int node = b * 256 + t;
  if (node < N) {
    dinv[node] = dv;
    offn[node] = e0 + excl;
  }
  pos[t] = e0 + excl;
  dl[t] = dv;
  __syncthreads();
  for (int e = e0 + t; e < e1; e += 256) {
    int2 a = raw[e];
    int cl = ((unsigned)a.x) >> 20;
    int p = atomicAdd(&pos[cl], 1);
    edat[p] = make_int2(a.x, __float_as_int(__int_as_float(a.y) * dl[cl]));
  }
}

// vfs = dinv .* vf   (row-scaled features for layer-1 aggregation)
__global__ __launch_bounds__(256) void k_scale(const float* __restrict__ vf,
                                               const float* __restrict__ dinv,
                                               float* __restrict__ vfs, int total) {
  int i = blockIdx.x * 256 + threadIdx.x;
  if (i < total) vfs[i] = vf[i] * dinv[i / 6];
}

// Layer-1 aggregation on scaled features; 8 lanes/node; read-only.
__global__ __launch_bounds__(256) void k_agg6(const float* __restrict__ vfs,
                                              const float* __restrict__ dinv,
                                              const int* __restrict__ offn,
                                              const int2* __restrict__ edat,
                                              float* __restrict__ Sx, int N) {
  int t = threadIdx.x, g = t >> 3, f = t & 7;
  int node = blockIdx.x * 32 + g;
  if (node >= N) return;
  bool act = f < 6;
  float dc = dinv[node];
  float acc = act ? dc * vfs[node * 6 + f] : 0.0f;  // dinv^2*vf = dinv*vfs
  int e1 = offn[node + 1];
  for (int e = offn[node]; e < e1; ++e) {
    int2 a = edat[e];
    if (act) acc += __int_as_float(a.y) * vfs[(a.x & RMASK) * 6 + f];
  }
  if (act) Sx[node * 6 + f] = acc;
}

// X(half) = sigmoid(Sx @ W1 + b1), Sx [N,6], W1 [6,64]
__global__ __launch_bounds__(256) void k_gemm1(const float* __restrict__ Sx,
                                               const float* __restrict__ W1,
                                               const float* __restrict__ b1,
                                               __half* __restrict__ X, int N) {
  __shared__ float Wl[6 * 64];
  __shared__ float bl[64];
  __shared__ float XT[6 * 65];
  int t = threadIdx.x;
  int n0 = blockIdx.x * 64;
  for (int i = t; i < 384; i += 256) {
    Wl[i] = W1[i];
    int n = i / 6, k = i - n * 6;
    int node = n0 + n;
    XT[k * 65 + n] = (node < N) ? Sx[node * 6 + k] : 0.0f;
  }
  if (t < 64) bl[t] = b1[t];
  __syncthreads();
  int c0 = (t & 15) * 4;
  int nn = (t >> 4) * 4;
  float acc[4][4];
#pragma unroll
  for (int i = 0; i < 4; ++i)
#pragma unroll
    for (int j = 0; j < 4; ++j) acc[i][j] = bl[c0 + j];
#pragma unroll
  for (int k = 0; k < 6; ++k) {
    float4 wv = *(const float4*)&Wl[k * 64 + c0];
    float xv[4];
#pragma unroll
    for (int i = 0; i < 4; ++i) xv[i] = XT[k * 65 + nn + i];
#pragma unroll
    for (int i = 0; i < 4; ++i) {
      acc[i][0] += xv[i] * wv.x;
      acc[i][1] += xv[i] * wv.y;
      acc[i][2] += xv[i] * wv.z;
      acc[i][3] += xv[i] * wv.w;
    }
  }
#pragma unroll
  for (int i = 0; i < 4; ++i) {
    int node = n0 + nn + i;
    if (node < N) {
      __half2* dst = (__half2*)(X + (size_t)node * 64 + c0);
      dst[0] = __floats2half2_rn(sigf(acc[i][0]), sigf(acc[i][1]));
      dst[1] = __floats2half2_rn(sigf(acc[i][2]), sigf(acc[i][3]));
    }
  }
}

// H'(half) = dinv .* (X(half) @ W(f32)). 64x64 tile per block.
__global__ __launch_bounds__(256) void k_gemm64(const __half* __restrict__ Xin,
                                                const float* __restrict__ W,
                                                const float* __restrict__ dinv,
                                                __half* __restrict__ Hout, int N) {
  __shared__ float XT[64 * 65];
  __shared__ float Wl[64 * 64];
  int t = threadIdx.x;
  int n0 = blockIdx.x * 64;
#pragma unroll
  for (int i = 0; i < 4; ++i) {
    int idx = (i * 256 + t) * 4;
    *(float4*)&Wl[idx] = *(const float4*)&W[idx];
  }
#pragma unroll
  for (int i = 0; i < 2; ++i) {
    int idx = (i * 256 + t) * 8;
    int n = idx >> 6, k = idx & 63;
    int node = n0 + n;
    __half2 hv[4];
    if (node < N) {
      const __half2* src = (const __half2*)(Xin + (size_t)node * 64 + k);
      hv[0] = src[0]; hv[1] = src[1]; hv[2] = src[2]; hv[3] = src[3];
    } else {
      hv[0] = hv[1] = hv[2] = hv[3] = __floats2half2_rn(0.f, 0.f);
    }
#pragma unroll
    for (int j = 0; j < 4; ++j) {
      float2 f = __half22float2(hv[j]);
      XT[(k + 2 * j) * 65 + n] = f.x;
      XT[(k + 2 * j + 1) * 65 + n] = f.y;
    }
  }
  __syncthreads();
  int c0 = (t & 15) * 4;
  int nn = (t >> 4) * 4;
  float acc[4][4] = {{0.f}};
#pragma unroll
  for (int k = 0; k < 64; ++k) {
    float4 wv = *(const float4*)&Wl[k * 64 + c0];
    float xv[4];
#pragma unroll
    for (int i = 0; i < 4; ++i) xv[i] = XT[k * 65 + nn + i];
#pragma unroll
    for (int i = 0; i < 4; ++i) {
      acc[i][0] += xv[i] * wv.x;
      acc[i][1] += xv[i] * wv.y;
      acc[i][2] += xv[i] * wv.z;
      acc[i][3] += xv[i] * wv.w;
    }
  }
#pragma unroll
  for (int i = 0; i < 4; ++i) {
    int node = n0 + nn + i;
    if (node < N) {
      float dv = dinv[node];
      __half2* dst = (__half2*)(Hout + (size_t)node * 64 + c0);
      dst[0] = __floats2half2_rn(dv * acc[i][0], dv * acc[i][1]);
      dst[1] = __floats2half2_rn(dv * acc[i][2], dv * acc[i][3]);
    }
  }
}

// Half-wave-per-node CSC gather agg on scaled fp16 H'; lane owns {2l,2l+1}.
// self-term: dinv[c]*H'[c] (= dinv^2*h). LAST: h5' = dinv * (x . W5).
template <bool LAST>
__global__ __launch_bounds__(256) void k_agg64(const __half* __restrict__ Hin,
                                               const float* __restrict__ dinv,
                                               const int* __restrict__ offn,
                                               const int2* __restrict__ edat,
                                               const float* __restrict__ b,
                                               const float* __restrict__ W5,
                                               __half* __restrict__ Xout,
                                               float* __restrict__ h5, int N) {
  const __half2* Hh = (const __half2*)Hin;  // [N][32] half2
  int t = threadIdx.x;
  int l = t & 31;
  int hw = t >> 5;
  int node = blockIdx.x * 8 + hw;
  if (node >= N) return;
  float di = dinv[node];
  float2 sf = __half22float2(Hh[(size_t)node * 32 + l]);
  float2 acc = make_float2(di * sf.x, di * sf.y);
  int e = offn[node], e1 = offn[node + 1];
  for (; e + 3 < e1; e += 4) {
    int2 a0 = edat[e];
    int2 a1 = edat[e + 1];
    int2 a2 = edat[e + 2];
    int2 a3 = edat[e + 3];
    float2 h0 = __half22float2(Hh[(size_t)(a0.x & RMASK) * 32 + l]);
    float2 h1 = __half22float2(Hh[(size_t)(a1.x & RMASK) * 32 + l]);
    float2 h2 = __half22float2(Hh[(size_t)(a2.x & RMASK) * 32 + l]);
    float2 h3 = __half22float2(Hh[(size_t)(a3.x & RMASK) * 32 + l]);
    float n0 = __int_as_float(a0.y), n1 = __int_as_float(a1.y);
    float n2 = __int_as_float(a2.y), n3 = __int_as_float(a3.y);
    acc.x += n0 * h0.x + n1 * h1.x + n2 * h2.x + n3 * h3.x;
    acc.y += n0 * h0.y + n1 * h1.y + n2 * h2.y + n3 * h3.y;
  }
  for (; e < e1; ++e) {
    int2 a = edat[e];
    float2 hv = __half22float2(Hh[(size_t)(a.x & RMASK) * 32 + l]);
    float nm = __int_as_float(a.y);
    acc.x += nm * hv.x;
    acc.y += nm * hv.y;
  }
  float2 bb = ((const float2*)b)[l];
  float x0 = sigf(acc.x + bb.x);
  float x1 = sigf(acc.y + bb.y);
  if (LAST) {
    float2 w5 = ((const float2*)W5)[l];
    float v = x0 * w5.x + x1 * w5.y;
#pragma unroll
    for (int d = 16; d; d >>= 1) v += __shfl_xor(v, d);
    if (l == 0) h5[node] = di * v;  // h5' = dinv * (x . W5)
  } else {
    ((__half2*)(Xout + (size_t)node * 64))[l] = __floats2half2_rn(x0, x1);
  }
}

// scalar CSC aggregation on h5' + sigmoid + per-block partial sum
__global__ __launch_bounds__(256) void k_agg5(const float* __restrict__ h5,
                                              const float* __restrict__ dinv,
                                              const int* __restrict__ offn,
                                              const int2* __restrict__ edat,
                                              const float* __restrict__ b5,
                                              float* __restrict__ partials, int N) {
  int n = blockIdx.x * 256 + threadIdx.x;
  float sig = 0.0f;
  if (n < N) {
    float di = dinv[n];
    float acc = di * h5[n];  // dinv^2 * (x.W5) = dinv * h5'
    int e1 = offn[n + 1];
    for (int e = offn[n]; e < e1; ++e) {
      int2 a = edat[e];
      acc += __int_as_float(a.y) * h5[a.x & RMASK];
    }
    sig = sigf(acc + b5[0]);
  }
#pragma unroll
  for (int d = 32; d; d >>= 1) sig += __shfl_xor(sig, d);
  __shared__ float ws[4];
  int lane = threadIdx.x & 63, wid = threadIdx.x >> 6;
  if (lane == 0) ws[wid] = sig;
  __syncthreads();
  if (threadIdx.x == 0) partials[blockIdx.x] = ws[0] + ws[1] + ws[2] + ws[3];
}

__global__ __launch_bounds__(512) void k_final(const float* __restrict__ partials,
                                               float* __restrict__ out, int nb,
                                               float invN) {
  float v = 0.0f;
  for (int i = threadIdx.x; i < nb; i += 512) v += partials[i];
#pragma unroll
  for (int d = 32; d; d >>= 1) v += __shfl_xor(v, d);
  __shared__ float ws[8];
  int lane = threadIdx.x & 63, wid = threadIdx.x >> 6;
  if (lane == 0) ws[wid] = v;
  __syncthreads();
  if (threadIdx.x == 0) {
    float s = 0.0f;
    for (int i = 0; i < 8; ++i) s += ws[i];
    out[0] = s * invN;
  }
}

extern "C" void kernel_launch(void* const* d_in, const int* in_sizes, int n_in,
                              void* d_out, int out_size, void* d_ws, size_t ws_size,
                              hipStream_t stream) {
  const float* vf = (const float*)d_in[0];
  const int* edges = (const int*)d_in[1];
  const float* w = (const float*)d_in[2];
  const float* W1 = (const float*)d_in[3];
  const float* b1 = (const float*)d_in[4];
  const float* W2 = (const float*)d_in[5];
  const float* b2 = (const float*)d_in[6];
  const float* W3 = (const float*)d_in[7];
  const float* b3 = (const float*)d_in[8];
  const float* W4 = (const float*)d_in[9];
  const float* b4 = (const float*)d_in[10];
  const float* W5 = (const float*)d_in[11];
  const float* b5 = (const float*)d_in[12];
  float* out = (float*)d_out;

  const int N = in_sizes[0] / 6;
  const int E = in_sizes[2];
  const int* row = edges;
  const int* col = edges + E;
  const int NB = (N + 255) >> 8;
  const int M = NB * SUBS;
  const int tiles = (E + (1 << TILE_SHIFT) - 1) >> TILE_SHIFT;

  size_t o = 0;
  auto carve = [&](size_t bytes) -> void* {
    void* p = (char*)d_ws + o;
    o += (bytes + 255) & ~(size_t)255;
    return p;
  };
  __half* X = (__half*)carve((size_t)N * 64 * 2);
  size_t hbytes = (size_t)N * 64 * 2;  // fp16 H'
  size_t rbytes = (size_t)E * 8;
  __half* H = (__half*)carve(hbytes > rbytes ? hbytes : rbytes);  // raw overlays H
  int2* raw = (int2*)H;
  int2* edat = (int2*)carve((size_t)E * 8);
  float* Sx = (float*)carve((size_t)N * 6 * 4);
  float* vfs = (float*)carve((size_t)N * 6 * 4);
  float* dinv = (float*)carve((size_t)N * 4);
  int* boff = (int*)carve((size_t)(M + 1) * 4);
  int* bnextp = (int*)carve((size_t)M * 16 * 4);  // line-padded cursors
  int* gcnt = (int*)carve((size_t)M * 4);
  int* gtile = (int*)carve((size_t)tiles * NB * 4);
  int* offn = (int*)carve((size_t)(N + 1) * 4);
  float* h5 = (float*)carve((size_t)N * 4);
  const int nb5 = (N + 255) / 256;
  float* partials = (float*)carve((size_t)nb5 * 4);

  hipMemsetAsync(gcnt, 0, (size_t)M * 4, stream);

  k_count<<<tiles, 256, 0, stream>>>(col, gcnt, gtile, E, NB);
  k_bscan<<<1, 1024, 0, stream>>>(gcnt, boff, bnextp, offn, M, N);
  k_tscatter<<<tiles, 256, 0, stream>>>(row, col, w, gtile, bnextp, raw, E, NB);
  k_bsort<<<NB, 256, 0, stream>>>(raw, boff, edat, offn, dinv, N);

  // layer 1: scaled features, aggregate (D=6), dense 6->64 (fp16 X out)
  k_scale<<<(N * 6 + 255) / 256, 256, 0, stream>>>(vf, dinv, vfs, N * 6);
  k_agg6<<<(N + 31) / 32, 256, 0, stream>>>(vfs, dinv, offn, edat, Sx, N);
  k_gemm1<<<(N + 63) / 64, 256, 0, stream>>>(Sx, W1, b1, X, N);

  // layers 2-4 (H overwrites raw, which is fully consumed by k_bsort)
  const int nbA = (N + 7) / 8;
  k_gemm64<<<(N + 63) / 64, 256, 0, stream>>>(X, W2, dinv, H, N);
  k_agg64<false><<<nbA, 256, 0, stream>>>(H, dinv, offn, edat, b2, W5, X, h5, N);
  k_gemm64<<<(N + 63) / 64, 256, 0, stream>>>(X, W3, dinv, H, N);
  k_agg64<false><<<nbA, 256, 0, stream>>>(H, dinv, offn, edat, b3, W5, X, h5, N);
  k_gemm64<<<(N + 63) / 64, 256, 0, stream>>>(X, W4, dinv, H, N);
  k_agg64<true><<<nbA, 256, 0, stream>>>(H, dinv, offn, edat, b4, W5, X, h5, N);

  // layer 5: scalar aggregation + mean
  k_agg5<<<nb5, 256, 0, stream>>>(h5, dinv, offn, edat, b5, partials, N);
  k_final<<<1, 512, 0, stream>>>(partials, out, nb5, 1.0f / (float)N);
}